// Round 2
// baseline (404.477 us; speedup 1.0000x reference)
//
#include <hip/hip_runtime.h>
#include <hip/hip_bf16.h>
#include <stdint.h>

// ---------------------------------------------------------------------------
// DecoderOnlyTransformer: x@Wq/Wk/Wv -> transposed-softmax attention -> @Wo
//   -> l2norm -> @Wff -> l2norm -> gelu(exact).  fp32 accum, bf16 MFMA core.
// B=2 S=2048 D=L=1024 H=16 dh=64.
// Input/output dtype (f32 vs bf16) auto-detected at runtime -> flag in ws.
// ---------------------------------------------------------------------------

typedef __attribute__((ext_vector_type(8))) short short8;   // 8 x bf16 (4 VGPRs)
typedef __attribute__((ext_vector_type(4))) float floatx4;  // MFMA accumulator

#define MFMA_BF16(a, b, c) __builtin_amdgcn_mfma_f32_16x16x32_bf16((a), (b), (c), 0, 0, 0)

__device__ __forceinline__ float bf2f(unsigned short u) {
  union { unsigned int i; float f; } v; v.i = ((unsigned int)u) << 16; return v.f;
}
__device__ __forceinline__ unsigned short f2bf(float f) {
  __hip_bfloat16 h = __float2bfloat16(f);
  return *reinterpret_cast<unsigned short*>(&h);
}
// async global->LDS, 16B per lane; lds dest must be wave-uniform (HW adds lane*16)
__device__ __forceinline__ void gld_lds16(const void* g, void* l) {
  __builtin_amdgcn_global_load_lds((__attribute__((address_space(1))) void*)g,
                                   (__attribute__((address_space(3))) void*)l,
                                   16, 0, 0);
}

// ---------------------------------------------------------------------------
// Dtype sniffing: for packed-bf16 data the LOW 16 bits of each u32 word are a
// valid bf16 (exponent in the sane range ~[96,144] for ~N(0,*) data); for f32
// data those bits are low mantissa noise (exponent-field ~uniform, ~20% pass).
// flag=1: bf16 inputs; flag=0: f32 inputs.
// ---------------------------------------------------------------------------
__global__ __launch_bounds__(256) void detect_dtype(const unsigned int* __restrict__ x,
                                                    int* __restrict__ flag)
{
  __shared__ int red[4];
  int ok = 0;
  for (int i = 0; i < 16; ++i) {
    const unsigned int w = x[threadIdx.x * 16 + i];
    const unsigned int e = (w >> 7) & 0xFF;   // exponent field of low-half bf16
    ok += (e == 0 || (e >= 96 && e <= 144)) ? 1 : 0;
  }
  for (int off = 32; off > 0; off >>= 1) ok += __shfl_down(ok, off, 64);
  if ((threadIdx.x & 63) == 0) red[threadIdx.x >> 6] = ok;
  __syncthreads();
  if (threadIdx.x == 0)
    *flag = ((red[0] + red[1] + red[2] + red[3]) > 2048) ? 1 : 0;
}

// x -> canonical bf16 (8 elements/thread, 4096*1024 total)
__global__ __launch_bounds__(256) void cvt_x(const void* __restrict__ src,
                                             unsigned short* __restrict__ dst,
                                             const int* __restrict__ flag)
{
  const int i = blockIdx.x * 256 + threadIdx.x;
  if (*flag) {
    ((uint4*)dst)[i] = ((const uint4*)src)[i];
  } else {
    const float4 a = ((const float4*)src)[2 * i];
    const float4 b = ((const float4*)src)[2 * i + 1];
    unsigned short o[8] = {f2bf(a.x), f2bf(a.y), f2bf(a.z), f2bf(a.w),
                           f2bf(b.x), f2bf(b.y), f2bf(b.z), f2bf(b.w)};
    ((uint4*)dst)[i] = *(uint4*)o;
  }
}

// ---------------------------------------------------------------------------
// Generic C[M,N] = A[M,K] @ Bt[N,K]^T, bf16 in/out, fp32 accum.
// Tile 128x64, BK=32, 4 waves; wave w does rows [32w,32w+32) x all 64 cols.
// ---------------------------------------------------------------------------
__global__ __launch_bounds__(256) void gemm_bt_128x64(
    const unsigned short* __restrict__ A, const unsigned short* __restrict__ Bt,
    unsigned short* __restrict__ C, int M, int N, int K, int lda, int ldb, int ldc)
{
  __shared__ __align__(16) unsigned short sA[128 * 32];  // 8 KB, no pad (global_load_lds)
  __shared__ __align__(16) unsigned short sB[64 * 32];   // 4 KB
  const int tid = threadIdx.x;
  const int wave = tid >> 6, lane = tid & 63, l15 = lane & 15, quad = lane >> 4;
  const int m0 = blockIdx.x * 128, n0 = blockIdx.y * 64;

  const floatx4 z4 = {0.f, 0.f, 0.f, 0.f};
  floatx4 acc[2][4];
  for (int i = 0; i < 2; ++i) for (int j = 0; j < 4; ++j) acc[i][j] = z4;

  const int NK = K >> 5;
  auto stage = [&](int kt) {
    const int k0 = kt << 5;
    for (int j = 0; j < 2; ++j) {            // A tile: 512 16B-chunks, 2 issues/wave
      const int ci = j * 256 + wave * 64 + lane;   // row = ci>>2, chunk = ci&3
      gld_lds16(A + (size_t)(m0 + (ci >> 2)) * lda + k0 + (ci & 3) * 8,
                &sA[(j * 256 + wave * 64) * 8]);
    }
    {                                        // B tile: 256 chunks, 1 issue/wave
      const int ci = wave * 64 + lane;
      gld_lds16(Bt + (size_t)(n0 + (ci >> 2)) * ldb + k0 + (ci & 3) * 8,
                &sB[(wave * 64) * 8]);
    }
  };

  stage(0);
  for (int kt = 0; kt < NK; ++kt) {
    __syncthreads();                         // staging of kt visible
    short8 af[2], bf[4];
    for (int mt = 0; mt < 2; ++mt)           // A[m=l15][k=quad*8+j]
      af[mt] = *(const short8*)&sA[(wave * 32 + mt * 16 + l15) * 32 + quad * 8];
    for (int nt = 0; nt < 4; ++nt)           // B[k][n=l15] = Bt[n][k]
      bf[nt] = *(const short8*)&sB[(nt * 16 + l15) * 32 + quad * 8];
    for (int mt = 0; mt < 2; ++mt)
      for (int nt = 0; nt < 4; ++nt)
        acc[mt][nt] = MFMA_BF16(af[mt], bf[nt], acc[mt][nt]);
    __syncthreads();                         // all reads done before overwrite
    if (kt + 1 < NK) stage(kt + 1);
  }
  // C/D layout: lane holds D[row=quad*4+r][col=l15]
  for (int mt = 0; mt < 2; ++mt)
    for (int nt = 0; nt < 4; ++nt)
      for (int r = 0; r < 4; ++r) {
        const int row = m0 + wave * 32 + mt * 16 + quad * 4 + r;
        const int col = n0 + nt * 16 + l15;
        C[(size_t)row * ldc + col] = f2bf(acc[mt][nt][r]);
      }
}

// ---------------------------------------------------------------------------
// 64x64-tile transpose (+dtype convert), WT[c][r] = W[r][c]  (square 1024x1024)
// ---------------------------------------------------------------------------
__global__ __launch_bounds__(256) void w_transpose(const void* __restrict__ W,
                                                   unsigned short* __restrict__ WT,
                                                   const int* __restrict__ flag)
{
  __shared__ __align__(16) unsigned short tile[64 * 72];
  const int rb = blockIdx.x * 64, cb = blockIdx.y * 64;
  const int tid = threadIdx.x;
  const int r = tid >> 2, c = tid & 3;
  unsigned short tmp[16];
  if (*flag) {
    const unsigned short* src = (const unsigned short*)W + (size_t)(rb + r) * 1024 + cb + c * 16;
    *(uint4*)&tmp[0] = *(const uint4*)src;
    *(uint4*)&tmp[8] = *(const uint4*)(src + 8);
  } else {
    const float* src = (const float*)W + (size_t)(rb + r) * 1024 + cb + c * 16;
    for (int j = 0; j < 16; j += 4) {
      const float4 f = *(const float4*)(src + j);
      tmp[j + 0] = f2bf(f.x); tmp[j + 1] = f2bf(f.y);
      tmp[j + 2] = f2bf(f.z); tmp[j + 3] = f2bf(f.w);
    }
  }
  *(uint4*)&tile[r * 72 + c * 16] = *(uint4*)&tmp[0];
  *(uint4*)&tile[r * 72 + c * 16 + 8] = *(uint4*)&tmp[8];
  __syncthreads();
  const int oc = tid >> 2;
  unsigned short out[16];
  for (int j = 0; j < 16; ++j) out[j] = tile[(c * 16 + j) * 72 + oc];
  unsigned short* dst = WT + (size_t)(cb + oc) * 1024 + rb + c * 16;
  *(uint4*)dst = *(uint4*)&out[0];
  *(uint4*)(dst + 8) = *(uint4*)&out[8];
}

// ---------------------------------------------------------------------------
// V-transpose: QKV[b*2048+s][2048+h*64+d] -> Vt[bh][d][s]  (k-contiguous rows)
// ---------------------------------------------------------------------------
__global__ __launch_bounds__(256) void v_transpose(const unsigned short* __restrict__ QKV,
                                                   unsigned short* __restrict__ Vt)
{
  __shared__ __align__(16) unsigned short tile[64 * 72];
  const int bh = blockIdx.x, st = blockIdx.y;       // s-tile of 64
  const int b = bh >> 4, h = bh & 15;
  const int tid = threadIdx.x;
  const int r = tid >> 2, c = tid & 3;
  const unsigned short* src =
      QKV + (size_t)(b * 2048 + st * 64 + r) * 3072 + 2048 + h * 64 + c * 16;
  *(uint4*)&tile[r * 72 + c * 16] = *(const uint4*)src;
  *(uint4*)&tile[r * 72 + c * 16 + 8] = *(const uint4*)(src + 8);
  __syncthreads();
  const int d = tid >> 2;
  unsigned short out[16];
  for (int j = 0; j < 16; ++j) out[j] = tile[(c * 16 + j) * 72 + d];
  unsigned short* dst = Vt + (size_t)bh * 64 * 2048 + (size_t)d * 2048 + st * 64 + c * 16;
  *(uint4*)dst = *(uint4*)&out[0];
  *(uint4*)(dst + 8) = *(uint4*)&out[8];
}

// ---------------------------------------------------------------------------
// Attention stats: per (bh, key k): m_k = max_q S[k,q], r_k = 1/sum_q exp(S-m)
// S[k,q] = <K_k, Q_q>/32.  MFMA K@Q^T; one exp per element online update.
// grid (32 bh, 16 kblocks of 128), 4 waves x 32 k-rows.
// ---------------------------------------------------------------------------
__global__ __launch_bounds__(256) void attn_stats(const unsigned short* __restrict__ QKV,
                                                  float* __restrict__ sm, float* __restrict__ sr)
{
  const int bh = blockIdx.x, kb = blockIdx.y;
  const int b = bh >> 4, h = bh & 15;
  const int tid = threadIdx.x;
  const int wave = tid >> 6, lane = tid & 63, l15 = lane & 15, quad = lane >> 4;
  const int kbase = kb * 128 + wave * 32;
  const size_t row0 = (size_t)b * 2048;
  const int qoff = h * 64, koff = 1024 + h * 64;

  short8 kf[2][2];  // A-operand: K rows, held for whole kernel
  for (int rt = 0; rt < 2; ++rt)
    for (int ks = 0; ks < 2; ++ks)
      kf[rt][ks] = *(const short8*)&QKV[(row0 + kbase + rt * 16 + l15) * 3072 +
                                        koff + ks * 32 + quad * 8];

  float m[2][4], l[2][4];
  for (int rt = 0; rt < 2; ++rt)
    for (int r = 0; r < 4; ++r) { m[rt][r] = -3.0e38f; l[rt][r] = 0.f; }

  const floatx4 z4 = {0.f, 0.f, 0.f, 0.f};
  for (int qt = 0; qt < 128; ++qt) {
    short8 qf[2];  // B-operand: B[k][n=q] = Q[q][k]
    for (int ks = 0; ks < 2; ++ks)
      qf[ks] = *(const short8*)&QKV[(row0 + qt * 16 + l15) * 3072 +
                                    qoff + ks * 32 + quad * 8];
    for (int rt = 0; rt < 2; ++rt) {
      floatx4 acc = z4;
      acc = MFMA_BF16(kf[rt][0], qf[0], acc);
      acc = MFMA_BF16(kf[rt][1], qf[1], acc);
      for (int r = 0; r < 4; ++r) {
        const float s = acc[r] * 0.03125f;         // /sqrt(1024)
        const float d = s - m[rt][r];
        const float e = __expf(-fabsf(d));         // single exp per element
        l[rt][r] = (d > 0.f) ? fmaf(l[rt][r], e, 1.0f) : (l[rt][r] + e);
        m[rt][r] = fmaxf(m[rt][r], s);
      }
    }
  }
  // merge the 16 column-subsets (lanes sharing quad) via butterfly
  for (int rt = 0; rt < 2; ++rt)
    for (int r = 0; r < 4; ++r) {
      float mm = m[rt][r], ll = l[rt][r];
      for (int off = 1; off < 16; off <<= 1) {
        const float om = __shfl_xor(mm, off, 64);
        const float ol = __shfl_xor(ll, off, 64);
        const float mn = fmaxf(mm, om);
        ll = ll * __expf(mm - mn) + ol * __expf(om - mn);
        mm = mn;
      }
      if (l15 == 0) {
        const int krow = kbase + rt * 16 + quad * 4 + r;
        sm[bh * 2048 + krow] = mm;
        sr[bh * 2048 + krow] = 1.0f / ll;
      }
    }
}

// ---------------------------------------------------------------------------
// Attention PV: Out[q,d] = sum_k exp(<Q_q,K_k>/32 - m_k) * r_k * V[k,d]
// grid (32 bh, 16 q-blocks of 128); k-tiles of 64; P LDS round-trip (C->A layout).
// Writes merged-head z1[b*2048+q][h*64+d].
// ---------------------------------------------------------------------------
__global__ __launch_bounds__(256) void attn_pv(const unsigned short* __restrict__ QKV,
                                               const unsigned short* __restrict__ Vt,
                                               const float* __restrict__ sm,
                                               const float* __restrict__ sr,
                                               unsigned short* __restrict__ Z1)
{
  __shared__ __align__(16) unsigned short sP[128 * 72];  // 18 KB, +8 pad breaks conflicts
  const int bh = blockIdx.x, qb = blockIdx.y;
  const int b = bh >> 4, h = bh & 15;
  const int tid = threadIdx.x;
  const int wave = tid >> 6, lane = tid & 63, l15 = lane & 15, quad = lane >> 4;
  const size_t row0 = (size_t)b * 2048;
  const int qoff = h * 64, koff = 1024 + h * 64;
  const int q0 = qb * 128;

  short8 qf[2][2];  // A-operand Q frags for this wave's 32 q-rows (whole kernel)
  for (int mt = 0; mt < 2; ++mt)
    for (int ks = 0; ks < 2; ++ks)
      qf[mt][ks] = *(const short8*)&QKV[(row0 + q0 + wave * 32 + mt * 16 + l15) * 3072 +
                                        qoff + ks * 32 + quad * 8];

  const floatx4 z4 = {0.f, 0.f, 0.f, 0.f};
  floatx4 acco[2][4];
  for (int i = 0; i < 2; ++i) for (int j = 0; j < 4; ++j) acco[i][j] = z4;

  const unsigned short* VtB = Vt + (size_t)bh * 64 * 2048;
  const float* smB = sm + bh * 2048;
  const float* srB = sr + bh * 2048;

  for (int kt = 0; kt < 32; ++kt) {
    const int kb = kt * 64;
    // --- S^T tile [q:32/wave][k:64] = Q @ K^T (registers only) ---
    floatx4 sacc[2][4];
    for (int nt = 0; nt < 4; ++nt) {
      const short8 kf0 = *(const short8*)&QKV[(row0 + kb + nt * 16 + l15) * 3072 + koff + quad * 8];
      const short8 kf1 = *(const short8*)&QKV[(row0 + kb + nt * 16 + l15) * 3072 + koff + 32 + quad * 8];
      for (int mt = 0; mt < 2; ++mt) {
        floatx4 a = z4;
        a = MFMA_BF16(qf[mt][0], kf0, a);
        a = MFMA_BF16(qf[mt][1], kf1, a);
        sacc[mt][nt] = a;
      }
    }
    __syncthreads();  // previous iter's P reads complete before overwrite
    // --- P = exp(S/32 - m_col)*r_col, write to LDS in A-readable layout ---
    for (int nt = 0; nt < 4; ++nt) {
      const float mc = smB[kb + nt * 16 + l15];
      const float rc = srB[kb + nt * 16 + l15];
      for (int mt = 0; mt < 2; ++mt)
        for (int r = 0; r < 4; ++r) {
          const float p = __expf(fmaf(sacc[mt][nt][r], 0.03125f, -mc)) * rc;
          const int qrow = wave * 32 + mt * 16 + quad * 4 + r;
          sP[qrow * 72 + nt * 16 + l15] = f2bf(p);
        }
    }
    __syncthreads();
    // --- Out += P @ V ---
    for (int ks = 0; ks < 2; ++ks) {
      short8 pf[2];
      for (int mt = 0; mt < 2; ++mt)
        pf[mt] = *(const short8*)&sP[(wave * 32 + mt * 16 + l15) * 72 + ks * 32 + quad * 8];
      for (int nt = 0; nt < 4; ++nt) {
        const short8 vf = *(const short8*)&VtB[(nt * 16 + l15) * 2048 + kb + ks * 32 + quad * 8];
        for (int mt = 0; mt < 2; ++mt)
          acco[mt][nt] = MFMA_BF16(pf[mt], vf, acco[mt][nt]);
      }
    }
  }
  for (int mt = 0; mt < 2; ++mt)
    for (int nt = 0; nt < 4; ++nt)
      for (int r = 0; r < 4; ++r) {
        const int q = q0 + wave * 32 + mt * 16 + quad * 4 + r;
        const int d = nt * 16 + l15;
        Z1[(row0 + q) * 1024 + qoff + d] = f2bf(acco[mt][nt][r]);
      }
}

// ---------------------------------------------------------------------------
// Row-wise L2 normalize (1024 cols), optional exact-erf GELU.  1 block/row.
// Final store obeys detected dtype (f32 vs bf16); intermediate stores bf16.
// ---------------------------------------------------------------------------
__global__ __launch_bounds__(256) void l2norm_gelu(const unsigned short* __restrict__ in,
                                                   void* __restrict__ out, int do_gelu,
                                                   int fin, const int* __restrict__ flag)
{
  __shared__ float red[4];
  const int row = blockIdx.x, tid = threadIdx.x;
  const unsigned short* p = in + (size_t)row * 1024 + tid * 4;
  const ushort4 u = *(const ushort4*)p;
  float x[4] = {bf2f(u.x), bf2f(u.y), bf2f(u.z), bf2f(u.w)};
  float ss = x[0] * x[0] + x[1] * x[1] + x[2] * x[2] + x[3] * x[3];
  for (int off = 32; off > 0; off >>= 1) ss += __shfl_down(ss, off, 64);
  if ((tid & 63) == 0) red[tid >> 6] = ss;
  __syncthreads();
  const float tot = red[0] + red[1] + red[2] + red[3];
  const float sc = 1.0f / fmaxf(sqrtf(tot), 1e-12f);
  float y[4];
  for (int j = 0; j < 4; ++j) {
    y[j] = x[j] * sc;
    if (do_gelu) y[j] = 0.5f * y[j] * (1.0f + erff(y[j] * 0.70710678118654752f));
  }
  if (fin && *flag == 0) {          // f32 output
    float4 o = {y[0], y[1], y[2], y[3]};
    ((float4*)out)[(size_t)row * 256 + tid] = o;
  } else {                          // bf16 output
    ushort4 o = {f2bf(y[0]), f2bf(y[1]), f2bf(y[2]), f2bf(y[3])};
    ((ushort4*)out)[(size_t)row * 256 + tid] = o;
  }
}

// ---------------------------------------------------------------------------
extern "C" void kernel_launch(void* const* d_in, const int* in_sizes, int n_in,
                              void* d_out, int out_size, void* d_ws, size_t ws_size,
                              hipStream_t stream)
{
  const void* x   = d_in[0];
  const void* Wq  = d_in[1];
  const void* Wk  = d_in[2];
  const void* Wv  = d_in[3];
  const void* Wo  = d_in[4];
  const void* Wff = d_in[5];

  char* ws = (char*)d_ws;
  size_t off = 0;
  auto alloc = [&](size_t bytes) -> void* {
    void* p = ws + off; off += (bytes + 255) & ~(size_t)255; return p;
  };
  int* flag             = (int*)alloc(256);
  unsigned short* xb    = (unsigned short*)alloc((size_t)4096 * 1024 * 2);  // 8 MB
  unsigned short* WTqkv = (unsigned short*)alloc((size_t)3072 * 1024 * 2);  // 6 MB
  unsigned short* WoT   = (unsigned short*)alloc((size_t)1024 * 1024 * 2);
  unsigned short* WffT  = (unsigned short*)alloc((size_t)1024 * 1024 * 2);
  unsigned short* QKV   = (unsigned short*)alloc((size_t)4096 * 3072 * 2);  // 24 MB
  unsigned short* Vt    = (unsigned short*)alloc((size_t)32 * 64 * 2048 * 2); // 8 MB
  float* sm             = (float*)alloc((size_t)32 * 2048 * 4);
  float* sr             = (float*)alloc((size_t)32 * 2048 * 4);
  unsigned short* z1    = (unsigned short*)alloc((size_t)4096 * 1024 * 2);  // 8 MB
  // aliases onto dead regions (total ws usage ~59 MB):
  unsigned short* z2  = Vt;    // Vt dead after attn_pv
  unsigned short* z2n = xb;    // xb dead after QKV gemm
  unsigned short* z3  = QKV;   // QKV dead after attn_pv

  detect_dtype<<<1, 256, 0, stream>>>((const unsigned int*)x, flag);
  cvt_x<<<2048, 256, 0, stream>>>(x, xb, flag);

  // weight transposes+convert (Bt layouts for gemm_bt)
  w_transpose<<<dim3(16, 16), 256, 0, stream>>>(Wq, WTqkv, flag);
  w_transpose<<<dim3(16, 16), 256, 0, stream>>>(Wk, WTqkv + (size_t)1024 * 1024, flag);
  w_transpose<<<dim3(16, 16), 256, 0, stream>>>(Wv, WTqkv + (size_t)2048 * 1024, flag);
  w_transpose<<<dim3(16, 16), 256, 0, stream>>>(Wo, WoT, flag);
  w_transpose<<<dim3(16, 16), 256, 0, stream>>>(Wff, WffT, flag);

  // fused QKV projection: [4096,1024]@[1024,3072] -> QKV [4096,3072]
  gemm_bt_128x64<<<dim3(32, 48), 256, 0, stream>>>(xb, WTqkv, QKV,
                                                   4096, 3072, 1024, 1024, 1024, 3072);
  v_transpose<<<dim3(32, 32), 256, 0, stream>>>(QKV, Vt);
  attn_stats<<<dim3(32, 16), 256, 0, stream>>>(QKV, sm, sr);
  attn_pv<<<dim3(32, 16), 256, 0, stream>>>(QKV, Vt, sm, sr, z1);

  gemm_bt_128x64<<<dim3(32, 16), 256, 0, stream>>>(z1, WoT, z2,
                                                   4096, 1024, 1024, 1024, 1024, 1024);
  l2norm_gelu<<<4096, 256, 0, stream>>>(z2, z2n, 0, 0, flag);
  gemm_bt_128x64<<<dim3(32, 16), 256, 0, stream>>>(z2n, WffT, z3,
                                                   4096, 1024, 1024, 1024, 1024, 1024);
  l2norm_gelu<<<4096, 256, 0, stream>>>(z3, d_out, 1, 1, flag);
}

// Round 3
// 331.634 us; speedup vs baseline: 1.2197x; 1.2197x over previous
//
#include <hip/hip_runtime.h>
#include <hip/hip_bf16.h>
#include <stdint.h>

// ---------------------------------------------------------------------------
// DecoderOnlyTransformer: x@Wq/Wk/Wv -> transposed-softmax attention -> @Wo
//   -> l2norm -> @Wff -> l2norm -> gelu(exact).  fp32 accum, bf16 MFMA core.
// B=2 S=2048 D=L=1024 H=16 dh=64.  Inputs are fp32 (auto-detected fallback).
// Softmax is over the QUERY axis (reference quirk); |scores| <= ~0.7 so the
// max-subtraction is dropped (mathematically identical softmax).
// ---------------------------------------------------------------------------

typedef __attribute__((ext_vector_type(8))) short short8;   // 8 x bf16 (4 VGPRs)
typedef __attribute__((ext_vector_type(4))) float floatx4;  // MFMA accumulator

#define MFMA_BF16(a, b, c) __builtin_amdgcn_mfma_f32_16x16x32_bf16((a), (b), (c), 0, 0, 0)

__device__ __forceinline__ float bf2f(unsigned short u) {
  union { unsigned int i; float f; } v; v.i = ((unsigned int)u) << 16; return v.f;
}
__device__ __forceinline__ unsigned short f2bf(float f) {
  __hip_bfloat16 h = __float2bfloat16(f);
  return *reinterpret_cast<unsigned short*>(&h);
}
// async global->LDS, 16B per lane; lds dest must be wave-uniform (HW adds lane*16)
__device__ __forceinline__ void gld_lds16(const void* g, void* l) {
  __builtin_amdgcn_global_load_lds((__attribute__((address_space(1))) void*)g,
                                   (__attribute__((address_space(3))) void*)l,
                                   16, 0, 0);
}

// ---------------------------------------------------------------------------
// Dtype sniffing: low 16 bits of each u32 look like sane bf16 only for packed
// bf16 data.  flag=1: bf16 inputs; flag=0: f32 inputs.
// ---------------------------------------------------------------------------
__global__ __launch_bounds__(256) void detect_dtype(const unsigned int* __restrict__ x,
                                                    int* __restrict__ flag)
{
  __shared__ int red[4];
  int ok = 0;
  for (int i = 0; i < 16; ++i) {
    const unsigned int w = x[threadIdx.x * 16 + i];
    const unsigned int e = (w >> 7) & 0xFF;
    ok += (e == 0 || (e >= 96 && e <= 144)) ? 1 : 0;
  }
  for (int off = 32; off > 0; off >>= 1) ok += __shfl_down(ok, off, 64);
  if ((threadIdx.x & 63) == 0) red[threadIdx.x >> 6] = ok;
  __syncthreads();
  if (threadIdx.x == 0)
    *flag = ((red[0] + red[1] + red[2] + red[3]) > 2048) ? 1 : 0;
}

// x -> canonical bf16 (8 elements/thread, 4096*1024 total)
__global__ __launch_bounds__(256) void cvt_x(const void* __restrict__ src,
                                             unsigned short* __restrict__ dst,
                                             const int* __restrict__ flag)
{
  const int i = blockIdx.x * 256 + threadIdx.x;
  if (*flag) {
    ((uint4*)dst)[i] = ((const uint4*)src)[i];
  } else {
    const float4 a = ((const float4*)src)[2 * i];
    const float4 b = ((const float4*)src)[2 * i + 1];
    unsigned short o[8] = {f2bf(a.x), f2bf(a.y), f2bf(a.z), f2bf(a.w),
                           f2bf(b.x), f2bf(b.y), f2bf(b.z), f2bf(b.w)};
    ((uint4*)dst)[i] = *(uint4*)o;
  }
}

// ---------------------------------------------------------------------------
// Generic C[M,N] = A[M,K] @ Bt[N,K]^T, bf16 in/out, fp32 accum.
// Tile 128x64, BK=32, 4 waves.
// ---------------------------------------------------------------------------
__global__ __launch_bounds__(256) void gemm_bt_128x64(
    const unsigned short* __restrict__ A, const unsigned short* __restrict__ Bt,
    unsigned short* __restrict__ C, int M, int N, int K, int lda, int ldb, int ldc)
{
  __shared__ __align__(16) unsigned short sA[128 * 32];
  __shared__ __align__(16) unsigned short sB[64 * 32];
  const int tid = threadIdx.x;
  const int wave = tid >> 6, lane = tid & 63, l15 = lane & 15, quad = lane >> 4;
  const int m0 = blockIdx.x * 128, n0 = blockIdx.y * 64;

  const floatx4 z4 = {0.f, 0.f, 0.f, 0.f};
  floatx4 acc[2][4];
  for (int i = 0; i < 2; ++i) for (int j = 0; j < 4; ++j) acc[i][j] = z4;

  const int NK = K >> 5;
  auto stage = [&](int kt) {
    const int k0 = kt << 5;
    for (int j = 0; j < 2; ++j) {
      const int ci = j * 256 + wave * 64 + lane;
      gld_lds16(A + (size_t)(m0 + (ci >> 2)) * lda + k0 + (ci & 3) * 8,
                &sA[(j * 256 + wave * 64) * 8]);
    }
    {
      const int ci = wave * 64 + lane;
      gld_lds16(Bt + (size_t)(n0 + (ci >> 2)) * ldb + k0 + (ci & 3) * 8,
                &sB[(wave * 64) * 8]);
    }
  };

  stage(0);
  for (int kt = 0; kt < NK; ++kt) {
    __syncthreads();
    short8 af[2], bf[4];
    for (int mt = 0; mt < 2; ++mt)
      af[mt] = *(const short8*)&sA[(wave * 32 + mt * 16 + l15) * 32 + quad * 8];
    for (int nt = 0; nt < 4; ++nt)
      bf[nt] = *(const short8*)&sB[(nt * 16 + l15) * 32 + quad * 8];
    for (int mt = 0; mt < 2; ++mt)
      for (int nt = 0; nt < 4; ++nt)
        acc[mt][nt] = MFMA_BF16(af[mt], bf[nt], acc[mt][nt]);
    __syncthreads();
    if (kt + 1 < NK) stage(kt + 1);
  }
  for (int mt = 0; mt < 2; ++mt)
    for (int nt = 0; nt < 4; ++nt)
      for (int r = 0; r < 4; ++r) {
        const int row = m0 + wave * 32 + mt * 16 + quad * 4 + r;
        const int col = n0 + nt * 16 + l15;
        C[(size_t)row * ldc + col] = f2bf(acc[mt][nt][r]);
      }
}

// ---------------------------------------------------------------------------
// 64x64-tile transpose (+dtype convert), WT[c][r] = W[r][c]  (square 1024x1024)
// ---------------------------------------------------------------------------
__global__ __launch_bounds__(256) void w_transpose(const void* __restrict__ W,
                                                   unsigned short* __restrict__ WT,
                                                   const int* __restrict__ flag)
{
  __shared__ __align__(16) unsigned short tile[64 * 72];
  const int rb = blockIdx.x * 64, cb = blockIdx.y * 64;
  const int tid = threadIdx.x;
  const int r = tid >> 2, c = tid & 3;
  unsigned short tmp[16];
  if (*flag) {
    const unsigned short* src = (const unsigned short*)W + (size_t)(rb + r) * 1024 + cb + c * 16;
    *(uint4*)&tmp[0] = *(const uint4*)src;
    *(uint4*)&tmp[8] = *(const uint4*)(src + 8);
  } else {
    const float* src = (const float*)W + (size_t)(rb + r) * 1024 + cb + c * 16;
    for (int j = 0; j < 16; j += 4) {
      const float4 f = *(const float4*)(src + j);
      tmp[j + 0] = f2bf(f.x); tmp[j + 1] = f2bf(f.y);
      tmp[j + 2] = f2bf(f.z); tmp[j + 3] = f2bf(f.w);
    }
  }
  *(uint4*)&tile[r * 72 + c * 16] = *(uint4*)&tmp[0];
  *(uint4*)&tile[r * 72 + c * 16 + 8] = *(uint4*)&tmp[8];
  __syncthreads();
  const int oc = tid >> 2;
  unsigned short out[16];
  for (int j = 0; j < 16; ++j) out[j] = tile[(c * 16 + j) * 72 + oc];
  unsigned short* dst = WT + (size_t)(cb + oc) * 1024 + rb + c * 16;
  *(uint4*)dst = *(uint4*)&out[0];
  *(uint4*)(dst + 8) = *(uint4*)&out[8];
}

// ---------------------------------------------------------------------------
// V-transpose: QKV[b*2048+s][2048+h*64+d] -> Vt[bh][d][s]
// ---------------------------------------------------------------------------
__global__ __launch_bounds__(256) void v_transpose(const unsigned short* __restrict__ QKV,
                                                   unsigned short* __restrict__ Vt)
{
  __shared__ __align__(16) unsigned short tile[64 * 72];
  const int bh = blockIdx.x, st = blockIdx.y;
  const int b = bh >> 4, h = bh & 15;
  const int tid = threadIdx.x;
  const int r = tid >> 2, c = tid & 3;
  const unsigned short* src =
      QKV + (size_t)(b * 2048 + st * 64 + r) * 3072 + 2048 + h * 64 + c * 16;
  *(uint4*)&tile[r * 72 + c * 16] = *(const uint4*)src;
  *(uint4*)&tile[r * 72 + c * 16 + 8] = *(const uint4*)(src + 8);
  __syncthreads();
  const int d = tid >> 2;
  unsigned short out[16];
  for (int j = 0; j < 16; ++j) out[j] = tile[(c * 16 + j) * 72 + d];
  unsigned short* dst = Vt + (size_t)bh * 64 * 2048 + (size_t)d * 2048 + st * 64 + c * 16;
  *(uint4*)dst = *(uint4*)&out[0];
  *(uint4*)(dst + 8) = *(uint4*)&out[8];
}

// ---------------------------------------------------------------------------
// Attention stats pass: partial sums  spart[qs][bh][k] = sum_{q in quarter}
// exp(<K_k,Q_q>/32).  No max subtraction (|S| < 1).  Barrier-free.
// grid (32 bh, 16 kb of 128, 4 q-quarters), 4 waves x 32 k-rows.
// ---------------------------------------------------------------------------
__global__ __launch_bounds__(256) void attn_stats(const unsigned short* __restrict__ QKV,
                                                  float* __restrict__ spart)
{
  const int bh = blockIdx.x, kb = blockIdx.y, qs = blockIdx.z;
  const int b = bh >> 4, h = bh & 15;
  const int tid = threadIdx.x;
  const int wave = tid >> 6, lane = tid & 63, l15 = lane & 15, quad = lane >> 4;
  const int kbase = kb * 128 + wave * 32;
  const size_t row0 = (size_t)b * 2048;
  const int qoff = h * 64, koff = 1024 + h * 64;
  const int qbase = qs * 512;

  short8 kf[2][2];  // A-operand: K rows, held for whole kernel
  for (int rt = 0; rt < 2; ++rt)
    for (int ks = 0; ks < 2; ++ks)
      kf[rt][ks] = *(const short8*)&QKV[(row0 + kbase + rt * 16 + l15) * 3072 +
                                        koff + ks * 32 + quad * 8];

  float l[2][4];
  for (int rt = 0; rt < 2; ++rt)
    for (int r = 0; r < 4; ++r) l[rt][r] = 0.f;

  const floatx4 z4 = {0.f, 0.f, 0.f, 0.f};
  for (int qt = 0; qt < 32; ++qt) {
    short8 qf[2];  // B-operand: B[d][n=q] = Q[q][d]
    for (int ks = 0; ks < 2; ++ks)
      qf[ks] = *(const short8*)&QKV[(row0 + qbase + qt * 16 + l15) * 3072 +
                                    qoff + ks * 32 + quad * 8];
    for (int rt = 0; rt < 2; ++rt) {
      floatx4 acc = z4;
      acc = MFMA_BF16(kf[rt][0], qf[0], acc);
      acc = MFMA_BF16(kf[rt][1], qf[1], acc);
      for (int r = 0; r < 4; ++r)
        l[rt][r] += __expf(acc[r] * 0.03125f);
    }
  }
  // sum across the 16 q-columns held by lanes sharing quad
  for (int rt = 0; rt < 2; ++rt)
    for (int r = 0; r < 4; ++r) {
      float ll = l[rt][r];
      ll += __shfl_xor(ll, 1, 64);
      ll += __shfl_xor(ll, 2, 64);
      ll += __shfl_xor(ll, 4, 64);
      ll += __shfl_xor(ll, 8, 64);
      if (l15 == 0) {
        const int krow = kbase + rt * 16 + quad * 4 + r;
        spart[(size_t)qs * 65536 + bh * 2048 + krow] = ll;
      }
    }
}

// rsum = 1 / (sum of 4 q-quarter partials), 65536 elements
__global__ __launch_bounds__(256) void stats_combine(const float* __restrict__ spart,
                                                     float* __restrict__ rsum)
{
  const int i = blockIdx.x * 256 + threadIdx.x;
  rsum[i] = 1.0f / (spart[i] + spart[i + 65536] + spart[i + 131072] + spart[i + 196608]);
}

// ---------------------------------------------------------------------------
// Attention PV: Out[q,d] = sum_k exp(<Q_q,K_k>/32) * rsum_k * V[k,d]
// grid (32 bh, 32 q-blocks of 64); k-tiles of 64 staged in LDS (XOR-swizzled
// chunks to kill bank conflicts under global_load_lds's no-padding rule).
// 4 waves x 16 q-rows.  Writes merged-head z1[b*2048+q][h*64+d].
// ---------------------------------------------------------------------------
__global__ __launch_bounds__(256) void attn_pv(const unsigned short* __restrict__ QKV,
                                               const unsigned short* __restrict__ Vt,
                                               const float* __restrict__ rsum,
                                               unsigned short* __restrict__ Z1)
{
  __shared__ __align__(16) unsigned short sK[64 * 64];  // 8 KB (rows k, cols dh)
  __shared__ __align__(16) unsigned short sV[64 * 64];  // 8 KB (rows d, cols k)
  __shared__ __align__(16) unsigned short sP[64 * 72];  // 9 KB (+pad)
  const int bh = blockIdx.x, qb = blockIdx.y;
  const int b = bh >> 4, h = bh & 15;
  const int tid = threadIdx.x;
  const int wave = tid >> 6, lane = tid & 63, l15 = lane & 15, quad = lane >> 4;
  const size_t row0 = (size_t)b * 2048;
  const int qoff = h * 64, koff = 1024 + h * 64;
  const int q0 = qb * 64;
  // staging source pattern: lane -> row lane>>3, chunk (lane&7)^((lane>>3)&7)
  const int srow = lane >> 3, schk = (lane & 7) ^ ((lane >> 3) & 7);

  short8 qf[2];  // A-operand Q frags for this wave's 16 q-rows
  for (int ks = 0; ks < 2; ++ks)
    qf[ks] = *(const short8*)&QKV[(row0 + q0 + wave * 16 + l15) * 3072 +
                                  qoff + ks * 32 + quad * 8];

  const floatx4 z4 = {0.f, 0.f, 0.f, 0.f};
  floatx4 acco[4];
  for (int j = 0; j < 4; ++j) acco[j] = z4;

  const unsigned short* VtB = Vt + (size_t)bh * 64 * 2048;
  const float* rsB = rsum + bh * 2048;

  for (int kt = 0; kt < 32; ++kt) {
    const int kb = kt * 64;
    __syncthreads();  // prev PV reads of sK/sV/sP done
    // stage K-tile (64 k-rows x 64 dh) and V-tile (64 d-rows x 64 k), swizzled
    for (int j = 0; j < 2; ++j) {
      const int jj = wave * 2 + j;  // 8-row group
      gld_lds16(QKV + (row0 + kb + jj * 8 + srow) * 3072 + koff + schk * 8, &sK[jj * 512]);
      gld_lds16(VtB + (size_t)(jj * 8 + srow) * 2048 + kb + schk * 8, &sV[jj * 512]);
    }
    __syncthreads();  // staging visible
    // --- S^T tile: rows q (this wave's 16), cols k (64) ---
    floatx4 sacc[4];
    for (int nt = 0; nt < 4; ++nt) {
      floatx4 a = z4;
      for (int ks = 0; ks < 2; ++ks) {
        const int row = nt * 16 + l15;                       // k-col index
        const int chk = (ks * 4 + quad) ^ (l15 & 7);         // swizzled dh-chunk
        const short8 kfr = *(const short8*)&sK[row * 64 + chk * 8];
        a = MFMA_BF16(qf[ks], kfr, a);
      }
      sacc[nt] = a;
    }
    // --- P = exp(S/32)*rsum_col -> LDS (C-layout -> A-layout) ---
    for (int nt = 0; nt < 4; ++nt) {
      const float rc = rsB[kb + nt * 16 + l15];
      for (int r = 0; r < 4; ++r) {
        const float p = __expf(sacc[nt][r] * 0.03125f) * rc;
        sP[(wave * 16 + quad * 4 + r) * 72 + nt * 16 + l15] = f2bf(p);
      }
    }
    __syncthreads();  // sP ready
    // --- Out += P @ V ---
    for (int ks = 0; ks < 2; ++ks) {
      const short8 pf = *(const short8*)&sP[(wave * 16 + l15) * 72 + ks * 32 + quad * 8];
      for (int nt = 0; nt < 4; ++nt) {
        const int row = nt * 16 + l15;                       // d index
        const int chk = (ks * 4 + quad) ^ (l15 & 7);         // swizzled k-chunk
        const short8 vf = *(const short8*)&sV[row * 64 + chk * 8];
        acco[nt] = MFMA_BF16(pf, vf, acco[nt]);
      }
    }
  }
  for (int nt = 0; nt < 4; ++nt)
    for (int r = 0; r < 4; ++r) {
      const int q = q0 + wave * 16 + quad * 4 + r;
      const int d = nt * 16 + l15;
      Z1[(row0 + q) * 1024 + qoff + d] = f2bf(acco[nt][r]);
    }
}

// ---------------------------------------------------------------------------
// Row-wise L2 normalize (1024 cols), optional exact-erf GELU.  1 block/row.
// ---------------------------------------------------------------------------
__global__ __launch_bounds__(256) void l2norm_gelu(const unsigned short* __restrict__ in,
                                                   void* __restrict__ out, int do_gelu,
                                                   int fin, const int* __restrict__ flag)
{
  __shared__ float red[4];
  const int row = blockIdx.x, tid = threadIdx.x;
  const unsigned short* p = in + (size_t)row * 1024 + tid * 4;
  const ushort4 u = *(const ushort4*)p;
  float x[4] = {bf2f(u.x), bf2f(u.y), bf2f(u.z), bf2f(u.w)};
  float ss = x[0] * x[0] + x[1] * x[1] + x[2] * x[2] + x[3] * x[3];
  for (int off = 32; off > 0; off >>= 1) ss += __shfl_down(ss, off, 64);
  if ((tid & 63) == 0) red[tid >> 6] = ss;
  __syncthreads();
  const float tot = red[0] + red[1] + red[2] + red[3];
  const float sc = 1.0f / fmaxf(sqrtf(tot), 1e-12f);
  float y[4];
  for (int j = 0; j < 4; ++j) {
    y[j] = x[j] * sc;
    if (do_gelu) y[j] = 0.5f * y[j] * (1.0f + erff(y[j] * 0.70710678118654752f));
  }
  if (fin && *flag == 0) {
    float4 o = {y[0], y[1], y[2], y[3]};
    ((float4*)out)[(size_t)row * 256 + tid] = o;
  } else {
    ushort4 o = {f2bf(y[0]), f2bf(y[1]), f2bf(y[2]), f2bf(y[3])};
    ((ushort4*)out)[(size_t)row * 256 + tid] = o;
  }
}

// ---------------------------------------------------------------------------
extern "C" void kernel_launch(void* const* d_in, const int* in_sizes, int n_in,
                              void* d_out, int out_size, void* d_ws, size_t ws_size,
                              hipStream_t stream)
{
  const void* x   = d_in[0];
  const void* Wq  = d_in[1];
  const void* Wk  = d_in[2];
  const void* Wv  = d_in[3];
  const void* Wo  = d_in[4];
  const void* Wff = d_in[5];

  char* ws = (char*)d_ws;
  size_t off = 0;
  auto alloc = [&](size_t bytes) -> void* {
    void* p = ws + off; off += (bytes + 255) & ~(size_t)255; return p;
  };
  int* flag             = (int*)alloc(256);
  unsigned short* xb    = (unsigned short*)alloc((size_t)4096 * 1024 * 2);  // 8 MB
  unsigned short* WTqkv = (unsigned short*)alloc((size_t)3072 * 1024 * 2);  // 6 MB
  unsigned short* WoT   = (unsigned short*)alloc((size_t)1024 * 1024 * 2);
  unsigned short* WffT  = (unsigned short*)alloc((size_t)1024 * 1024 * 2);
  unsigned short* QKV   = (unsigned short*)alloc((size_t)4096 * 3072 * 2);  // 24 MB
  unsigned short* Vt    = (unsigned short*)alloc((size_t)32 * 64 * 2048 * 2); // 8 MB
  float* spart          = (float*)alloc((size_t)4 * 65536 * 4);             // 1 MB
  float* rsum           = (float*)alloc((size_t)65536 * 4);                 // 256 KB
  unsigned short* z1    = (unsigned short*)alloc((size_t)4096 * 1024 * 2);  // 8 MB
  // aliases onto dead regions:
  unsigned short* z2  = Vt;    // Vt dead after attn_pv
  unsigned short* z2n = xb;    // xb dead after QKV gemm
  unsigned short* z3  = QKV;   // QKV dead after attn_pv

  detect_dtype<<<1, 256, 0, stream>>>((const unsigned int*)x, flag);
  cvt_x<<<2048, 256, 0, stream>>>(x, xb, flag);

  w_transpose<<<dim3(16, 16), 256, 0, stream>>>(Wq, WTqkv, flag);
  w_transpose<<<dim3(16, 16), 256, 0, stream>>>(Wk, WTqkv + (size_t)1024 * 1024, flag);
  w_transpose<<<dim3(16, 16), 256, 0, stream>>>(Wv, WTqkv + (size_t)2048 * 1024, flag);
  w_transpose<<<dim3(16, 16), 256, 0, stream>>>(Wo, WoT, flag);
  w_transpose<<<dim3(16, 16), 256, 0, stream>>>(Wff, WffT, flag);

  // fused QKV projection: [4096,1024]@[1024,3072] -> QKV [4096,3072]
  gemm_bt_128x64<<<dim3(32, 48), 256, 0, stream>>>(xb, WTqkv, QKV,
                                                   4096, 3072, 1024, 1024, 1024, 3072);
  v_transpose<<<dim3(32, 32), 256, 0, stream>>>(QKV, Vt);
  attn_stats<<<dim3(32, 16, 4), 256, 0, stream>>>(QKV, spart);
  stats_combine<<<256, 256, 0, stream>>>(spart, rsum);
  attn_pv<<<dim3(32, 32), 256, 0, stream>>>(QKV, Vt, rsum, z1);

  gemm_bt_128x64<<<dim3(32, 16), 256, 0, stream>>>(z1, WoT, z2,
                                                   4096, 1024, 1024, 1024, 1024, 1024);
  l2norm_gelu<<<4096, 256, 0, stream>>>(z2, z2n, 0, 0, flag);
  gemm_bt_128x64<<<dim3(32, 16), 256, 0, stream>>>(z2n, WffT, z3,
                                                   4096, 1024, 1024, 1024, 1024, 1024);
  l2norm_gelu<<<4096, 256, 0, stream>>>(z3, d_out, 1, 1, flag);
}

// Round 4
// 322.335 us; speedup vs baseline: 1.2548x; 1.0288x over previous
//
#include <hip/hip_runtime.h>
#include <hip/hip_bf16.h>
#include <stdint.h>

// ---------------------------------------------------------------------------
// DecoderOnlyTransformer: x@Wq/Wk/Wv -> transposed-softmax attention -> @Wo
//   -> l2norm -> @Wff -> l2norm -> gelu(exact).  fp32 accum, bf16 MFMA core.
// B=2 S=2048 D=L=1024 H=16 dh=64.  Inputs are fp32 (auto-detected fallback).
// Softmax is over the QUERY axis (reference quirk); |scores| <= ~0.7 so the
// max-subtraction is dropped (mathematically identical softmax).
// ---------------------------------------------------------------------------

typedef __attribute__((ext_vector_type(8))) short short8;   // 8 x bf16 (4 VGPRs)
typedef __attribute__((ext_vector_type(4))) float floatx4;  // MFMA accumulator

#define MFMA_BF16(a, b, c) __builtin_amdgcn_mfma_f32_16x16x32_bf16((a), (b), (c), 0, 0, 0)

__device__ __forceinline__ float bf2f(unsigned short u) {
  union { unsigned int i; float f; } v; v.i = ((unsigned int)u) << 16; return v.f;
}
__device__ __forceinline__ unsigned short f2bf(float f) {
  __hip_bfloat16 h = __float2bfloat16(f);
  return *reinterpret_cast<unsigned short*>(&h);
}
// async global->LDS, 16B per lane; lds dest is wave-uniform base + lane*16
__device__ __forceinline__ void gld_lds16(const void* g, void* l) {
  __builtin_amdgcn_global_load_lds((__attribute__((address_space(1))) void*)g,
                                   (__attribute__((address_space(3))) void*)l,
                                   16, 0, 0);
}

// ---------------------------------------------------------------------------
// Dtype sniffing: low 16 bits of each u32 look like sane bf16 only for packed
// bf16 data.  flag=1: bf16 inputs; flag=0: f32 inputs.
// ---------------------------------------------------------------------------
__global__ __launch_bounds__(256) void detect_dtype(const unsigned int* __restrict__ x,
                                                    int* __restrict__ flag)
{
  __shared__ int red[4];
  int ok = 0;
  for (int i = 0; i < 16; ++i) {
    const unsigned int w = x[threadIdx.x * 16 + i];
    const unsigned int e = (w >> 7) & 0xFF;
    ok += (e == 0 || (e >= 96 && e <= 144)) ? 1 : 0;
  }
  for (int off = 32; off > 0; off >>= 1) ok += __shfl_down(ok, off, 64);
  if ((threadIdx.x & 63) == 0) red[threadIdx.x >> 6] = ok;
  __syncthreads();
  if (threadIdx.x == 0)
    *flag = ((red[0] + red[1] + red[2] + red[3]) > 2048) ? 1 : 0;
}

// x -> canonical bf16 (8 elements/thread, 4096*1024 total)
__global__ __launch_bounds__(256) void cvt_x(const void* __restrict__ src,
                                             unsigned short* __restrict__ dst,
                                             const int* __restrict__ flag)
{
  const int i = blockIdx.x * 256 + threadIdx.x;
  if (*flag) {
    ((uint4*)dst)[i] = ((const uint4*)src)[i];
  } else {
    const float4 a = ((const float4*)src)[2 * i];
    const float4 b = ((const float4*)src)[2 * i + 1];
    unsigned short o[8] = {f2bf(a.x), f2bf(a.y), f2bf(a.z), f2bf(a.w),
                           f2bf(b.x), f2bf(b.y), f2bf(b.z), f2bf(b.w)};
    ((uint4*)dst)[i] = *(uint4*)o;
  }
}

// ---------------------------------------------------------------------------
// Generic C[M,N] = A[M,K] @ Bt[N,K]^T, bf16 in/out, fp32 accum.
// Tile 128x64, BK=32, 4 waves.
// ---------------------------------------------------------------------------
__global__ __launch_bounds__(256) void gemm_bt_128x64(
    const unsigned short* __restrict__ A, const unsigned short* __restrict__ Bt,
    unsigned short* __restrict__ C, int M, int N, int K, int lda, int ldb, int ldc)
{
  __shared__ __align__(16) unsigned short sA[128 * 32];
  __shared__ __align__(16) unsigned short sB[64 * 32];
  const int tid = threadIdx.x;
  const int wave = tid >> 6, lane = tid & 63, l15 = lane & 15, quad = lane >> 4;
  const int m0 = blockIdx.x * 128, n0 = blockIdx.y * 64;

  const floatx4 z4 = {0.f, 0.f, 0.f, 0.f};
  floatx4 acc[2][4];
  for (int i = 0; i < 2; ++i) for (int j = 0; j < 4; ++j) acc[i][j] = z4;

  const int NK = K >> 5;
  auto stage = [&](int kt) {
    const int k0 = kt << 5;
    for (int j = 0; j < 2; ++j) {
      const int ci = j * 256 + wave * 64 + lane;
      gld_lds16(A + (size_t)(m0 + (ci >> 2)) * lda + k0 + (ci & 3) * 8,
                &sA[(j * 256 + wave * 64) * 8]);
    }
    {
      const int ci = wave * 64 + lane;
      gld_lds16(Bt + (size_t)(n0 + (ci >> 2)) * ldb + k0 + (ci & 3) * 8,
                &sB[(wave * 64) * 8]);
    }
  };

  stage(0);
  for (int kt = 0; kt < NK; ++kt) {
    __syncthreads();
    short8 af[2], bf[4];
    for (int mt = 0; mt < 2; ++mt)
      af[mt] = *(const short8*)&sA[(wave * 32 + mt * 16 + l15) * 32 + quad * 8];
    for (int nt = 0; nt < 4; ++nt)
      bf[nt] = *(const short8*)&sB[(nt * 16 + l15) * 32 + quad * 8];
    for (int mt = 0; mt < 2; ++mt)
      for (int nt = 0; nt < 4; ++nt)
        acc[mt][nt] = MFMA_BF16(af[mt], bf[nt], acc[mt][nt]);
    __syncthreads();
    if (kt + 1 < NK) stage(kt + 1);
  }
  for (int mt = 0; mt < 2; ++mt)
    for (int nt = 0; nt < 4; ++nt)
      for (int r = 0; r < 4; ++r) {
        const int row = m0 + wave * 32 + mt * 16 + quad * 4 + r;
        const int col = n0 + nt * 16 + l15;
        C[(size_t)row * ldc + col] = f2bf(acc[mt][nt][r]);
      }
}

// ---------------------------------------------------------------------------
// 64x64-tile transpose (+dtype convert), WT[c][r] = W[r][c]  (square 1024x1024)
// ---------------------------------------------------------------------------
__global__ __launch_bounds__(256) void w_transpose(const void* __restrict__ W,
                                                   unsigned short* __restrict__ WT,
                                                   const int* __restrict__ flag)
{
  __shared__ __align__(16) unsigned short tile[64 * 72];
  const int rb = blockIdx.x * 64, cb = blockIdx.y * 64;
  const int tid = threadIdx.x;
  const int r = tid >> 2, c = tid & 3;
  unsigned short tmp[16];
  if (*flag) {
    const unsigned short* src = (const unsigned short*)W + (size_t)(rb + r) * 1024 + cb + c * 16;
    *(uint4*)&tmp[0] = *(const uint4*)src;
    *(uint4*)&tmp[8] = *(const uint4*)(src + 8);
  } else {
    const float* src = (const float*)W + (size_t)(rb + r) * 1024 + cb + c * 16;
    for (int j = 0; j < 16; j += 4) {
      const float4 f = *(const float4*)(src + j);
      tmp[j + 0] = f2bf(f.x); tmp[j + 1] = f2bf(f.y);
      tmp[j + 2] = f2bf(f.z); tmp[j + 3] = f2bf(f.w);
    }
  }
  *(uint4*)&tile[r * 72 + c * 16] = *(uint4*)&tmp[0];
  *(uint4*)&tile[r * 72 + c * 16 + 8] = *(uint4*)&tmp[8];
  __syncthreads();
  const int oc = tid >> 2;
  unsigned short out[16];
  for (int j = 0; j < 16; ++j) out[j] = tile[(c * 16 + j) * 72 + oc];
  unsigned short* dst = WT + (size_t)(cb + oc) * 1024 + rb + c * 16;
  *(uint4*)dst = *(uint4*)&out[0];
  *(uint4*)(dst + 8) = *(uint4*)&out[8];
}

// ---------------------------------------------------------------------------
// V-transpose: QKV[b*2048+s][2048+h*64+d] -> Vt[bh][d][s]
// ---------------------------------------------------------------------------
__global__ __launch_bounds__(256) void v_transpose(const unsigned short* __restrict__ QKV,
                                                   unsigned short* __restrict__ Vt)
{
  __shared__ __align__(16) unsigned short tile[64 * 72];
  const int bh = blockIdx.x, st = blockIdx.y;
  const int b = bh >> 4, h = bh & 15;
  const int tid = threadIdx.x;
  const int r = tid >> 2, c = tid & 3;
  const unsigned short* src =
      QKV + (size_t)(b * 2048 + st * 64 + r) * 3072 + 2048 + h * 64 + c * 16;
  *(uint4*)&tile[r * 72 + c * 16] = *(const uint4*)src;
  *(uint4*)&tile[r * 72 + c * 16 + 8] = *(const uint4*)(src + 8);
  __syncthreads();
  const int d = tid >> 2;
  unsigned short out[16];
  for (int j = 0; j < 16; ++j) out[j] = tile[(c * 16 + j) * 72 + d];
  unsigned short* dst = Vt + (size_t)bh * 64 * 2048 + (size_t)d * 2048 + st * 64 + c * 16;
  *(uint4*)dst = *(uint4*)&out[0];
  *(uint4*)(dst + 8) = *(uint4*)&out[8];
}

// ---------------------------------------------------------------------------
// Attention stats pass: spart[qs][bh][k] = sum_{q in 512-quarter} exp(S[k,q]),
// S = <K_k,Q_q>/32.  Q-tiles (64 q-rows) staged to LDS in FRAGMENT-MAJOR
// order via global_load_lds (lane's 16B at base+lane*16 IS its B-fragment),
// double-buffered, shared by all 4 waves.  One barrier per tile.
// grid (32 bh, 16 kb of 128, 4 q-quarters), 4 waves x 32 k-rows.
// ---------------------------------------------------------------------------
__global__ __launch_bounds__(256) void attn_stats(const unsigned short* __restrict__ QKV,
                                                  float* __restrict__ spart)
{
  __shared__ __align__(16) unsigned short sQ[2][8 * 512];  // 2 x 8 frags x 1 KB
  const int bh = blockIdx.x, kb = blockIdx.y, qs = blockIdx.z;
  const int b = bh >> 4, h = bh & 15;
  const int tid = threadIdx.x;
  const int wave = tid >> 6, lane = tid & 63, l15 = lane & 15, quad = lane >> 4;
  const int kbase = kb * 128 + wave * 32;
  const size_t row0 = (size_t)b * 2048;
  const int qoff = h * 64, koff = 1024 + h * 64;
  const int qbase = qs * 512;

  // A-operand: this wave's 32 K rows, held in registers for the whole kernel
  short8 kf[2][2];
  for (int rt = 0; rt < 2; ++rt)
    for (int ks = 0; ks < 2; ++ks)
      kf[rt][ks] = *(const short8*)&QKV[(row0 + kbase + rt * 16 + l15) * 3072 +
                                        koff + ks * 32 + quad * 8];

  float l[2][4];
  for (int rt = 0; rt < 2; ++rt)
    for (int r = 0; r < 4; ++r) l[rt][r] = 0.f;

  // stage q-tile t (64 rows) as 8 B-fragments; wave stages frags wave*2, wave*2+1
  auto stageQ = [&](int t) {
    const int qt0 = qbase + t * 64;
    for (int j = 0; j < 2; ++j) {
      const int f = wave * 2 + j;            // f = nt*2 + ks
      const int nt = f >> 1, ks = f & 1;
      gld_lds16(QKV + (row0 + qt0 + nt * 16 + l15) * 3072 + qoff + ks * 32 + quad * 8,
                &sQ[t & 1][f * 512]);
    }
  };

  const floatx4 z4 = {0.f, 0.f, 0.f, 0.f};
  stageQ(0);
  for (int t = 0; t < 8; ++t) {
    __syncthreads();                         // staging of t visible; t-1 reads done
    if (t + 1 < 8) stageQ(t + 1);            // prefetch into other buffer
    const unsigned short* sQt = sQ[t & 1];
    for (int nt = 0; nt < 4; ++nt) {
      const short8 bq0 = *(const short8*)&sQt[(nt * 2 + 0) * 512 + lane * 8];
      const short8 bq1 = *(const short8*)&sQt[(nt * 2 + 1) * 512 + lane * 8];
      for (int rt = 0; rt < 2; ++rt) {
        floatx4 acc = z4;
        acc = MFMA_BF16(kf[rt][0], bq0, acc);
        acc = MFMA_BF16(kf[rt][1], bq1, acc);
        for (int r = 0; r < 4; ++r)
          l[rt][r] += __expf(acc[r] * 0.03125f);
      }
    }
  }
  // sum across the 16 q-columns held by lanes sharing quad
  for (int rt = 0; rt < 2; ++rt)
    for (int r = 0; r < 4; ++r) {
      float ll = l[rt][r];
      ll += __shfl_xor(ll, 1, 64);
      ll += __shfl_xor(ll, 2, 64);
      ll += __shfl_xor(ll, 4, 64);
      ll += __shfl_xor(ll, 8, 64);
      if (l15 == 0) {
        const int krow = kbase + rt * 16 + quad * 4 + r;
        spart[(size_t)qs * 65536 + bh * 2048 + krow] = ll;
      }
    }
}

// rsum = 1 / (sum of 4 q-quarter partials), 65536 elements
__global__ __launch_bounds__(256) void stats_combine(const float* __restrict__ spart,
                                                     float* __restrict__ rsum)
{
  const int i = blockIdx.x * 256 + threadIdx.x;
  rsum[i] = 1.0f / (spart[i] + spart[i + 65536] + spart[i + 131072] + spart[i + 196608]);
}

// ---------------------------------------------------------------------------
// Attention PV: Out[q,d] = sum_k exp(<Q_q,K_k>/32) * rsum_k * V[k,d]
// grid (32 bh, 32 q-blocks of 64); k-tiles of 64 staged in LDS.
// 4 waves x 16 q-rows.  Writes merged-head z1[b*2048+q][h*64+d].
// ---------------------------------------------------------------------------
__global__ __launch_bounds__(256) void attn_pv(const unsigned short* __restrict__ QKV,
                                               const unsigned short* __restrict__ Vt,
                                               const float* __restrict__ rsum,
                                               unsigned short* __restrict__ Z1)
{
  __shared__ __align__(16) unsigned short sK[64 * 64];  // 8 KB (rows k, cols dh)
  __shared__ __align__(16) unsigned short sV[64 * 64];  // 8 KB (rows d, cols k)
  __shared__ __align__(16) unsigned short sP[64 * 72];  // 9 KB (+pad)
  const int bh = blockIdx.x, qb = blockIdx.y;
  const int b = bh >> 4, h = bh & 15;
  const int tid = threadIdx.x;
  const int wave = tid >> 6, lane = tid & 63, l15 = lane & 15, quad = lane >> 4;
  const size_t row0 = (size_t)b * 2048;
  const int qoff = h * 64, koff = 1024 + h * 64;
  const int q0 = qb * 64;
  const int srow = lane >> 3, schk = (lane & 7) ^ ((lane >> 3) & 7);

  short8 qf[2];  // A-operand Q frags for this wave's 16 q-rows
  for (int ks = 0; ks < 2; ++ks)
    qf[ks] = *(const short8*)&QKV[(row0 + q0 + wave * 16 + l15) * 3072 +
                                  qoff + ks * 32 + quad * 8];

  const floatx4 z4 = {0.f, 0.f, 0.f, 0.f};
  floatx4 acco[4];
  for (int j = 0; j < 4; ++j) acco[j] = z4;

  const unsigned short* VtB = Vt + (size_t)bh * 64 * 2048;
  const float* rsB = rsum + bh * 2048;

  for (int kt = 0; kt < 32; ++kt) {
    const int kb = kt * 64;
    __syncthreads();  // prev PV reads of sK/sV/sP done
    for (int j = 0; j < 2; ++j) {
      const int jj = wave * 2 + j;  // 8-row group
      gld_lds16(QKV + (row0 + kb + jj * 8 + srow) * 3072 + koff + schk * 8, &sK[jj * 512]);
      gld_lds16(VtB + (size_t)(jj * 8 + srow) * 2048 + kb + schk * 8, &sV[jj * 512]);
    }
    __syncthreads();  // staging visible
    // --- S^T tile: rows q (this wave's 16), cols k (64) ---
    floatx4 sacc[4];
    for (int nt = 0; nt < 4; ++nt) {
      floatx4 a = z4;
      for (int ks = 0; ks < 2; ++ks) {
        const int row = nt * 16 + l15;                       // k-col index
        const int chk = (ks * 4 + quad) ^ (l15 & 7);         // swizzled dh-chunk
        const short8 kfr = *(const short8*)&sK[row * 64 + chk * 8];
        a = MFMA_BF16(qf[ks], kfr, a);
      }
      sacc[nt] = a;
    }
    // --- P = exp(S/32)*rsum_col -> LDS (C-layout -> A-layout) ---
    for (int nt = 0; nt < 4; ++nt) {
      const float rc = rsB[kb + nt * 16 + l15];
      for (int r = 0; r < 4; ++r) {
        const float p = __expf(sacc[nt][r] * 0.03125f) * rc;
        sP[(wave * 16 + quad * 4 + r) * 72 + nt * 16 + l15] = f2bf(p);
      }
    }
    __syncthreads();  // sP ready
    // --- Out += P @ V ---
    for (int ks = 0; ks < 2; ++ks) {
      const short8 pf = *(const short8*)&sP[(wave * 16 + l15) * 72 + ks * 32 + quad * 8];
      for (int nt = 0; nt < 4; ++nt) {
        const int row = nt * 16 + l15;                       // d index
        const int chk = (ks * 4 + quad) ^ (l15 & 7);         // swizzled k-chunk
        const short8 vf = *(const short8*)&sV[row * 64 + chk * 8];
        acco[nt] = MFMA_BF16(pf, vf, acco[nt]);
      }
    }
  }
  for (int nt = 0; nt < 4; ++nt)
    for (int r = 0; r < 4; ++r) {
      const int q = q0 + wave * 16 + quad * 4 + r;
      const int d = nt * 16 + l15;
      Z1[(row0 + q) * 1024 + qoff + d] = f2bf(acco[nt][r]);
    }
}

// ---------------------------------------------------------------------------
// Row-wise L2 normalize (1024 cols), optional exact-erf GELU.  1 block/row.
// ---------------------------------------------------------------------------
__global__ __launch_bounds__(256) void l2norm_gelu(const unsigned short* __restrict__ in,
                                                   void* __restrict__ out, int do_gelu,
                                                   int fin, const int* __restrict__ flag)
{
  __shared__ float red[4];
  const int row = blockIdx.x, tid = threadIdx.x;
  const unsigned short* p = in + (size_t)row * 1024 + tid * 4;
  const ushort4 u = *(const ushort4*)p;
  float x[4] = {bf2f(u.x), bf2f(u.y), bf2f(u.z), bf2f(u.w)};
  float ss = x[0] * x[0] + x[1] * x[1] + x[2] * x[2] + x[3] * x[3];
  for (int off = 32; off > 0; off >>= 1) ss += __shfl_down(ss, off, 64);
  if ((tid & 63) == 0) red[tid >> 6] = ss;
  __syncthreads();
  const float tot = red[0] + red[1] + red[2] + red[3];
  const float sc = 1.0f / fmaxf(sqrtf(tot), 1e-12f);
  float y[4];
  for (int j = 0; j < 4; ++j) {
    y[j] = x[j] * sc;
    if (do_gelu) y[j] = 0.5f * y[j] * (1.0f + erff(y[j] * 0.70710678118654752f));
  }
  if (fin && *flag == 0) {
    float4 o = {y[0], y[1], y[2], y[3]};
    ((float4*)out)[(size_t)row * 256 + tid] = o;
  } else {
    ushort4 o = {f2bf(y[0]), f2bf(y[1]), f2bf(y[2]), f2bf(y[3])};
    ((ushort4*)out)[(size_t)row * 256 + tid] = o;
  }
}

// ---------------------------------------------------------------------------
extern "C" void kernel_launch(void* const* d_in, const int* in_sizes, int n_in,
                              void* d_out, int out_size, void* d_ws, size_t ws_size,
                              hipStream_t stream)
{
  const void* x   = d_in[0];
  const void* Wq  = d_in[1];
  const void* Wk  = d_in[2];
  const void* Wv  = d_in[3];
  const void* Wo  = d_in[4];
  const void* Wff = d_in[5];

  char* ws = (char*)d_ws;
  size_t off = 0;
  auto alloc = [&](size_t bytes) -> void* {
    void* p = ws + off; off += (bytes + 255) & ~(size_t)255; return p;
  };
  int* flag             = (int*)alloc(256);
  unsigned short* xb    = (unsigned short*)alloc((size_t)4096 * 1024 * 2);  // 8 MB
  unsigned short* WTqkv = (unsigned short*)alloc((size_t)3072 * 1024 * 2);  // 6 MB
  unsigned short* WoT   = (unsigned short*)alloc((size_t)1024 * 1024 * 2);
  unsigned short* WffT  = (unsigned short*)alloc((size_t)1024 * 1024 * 2);
  unsigned short* QKV   = (unsigned short*)alloc((size_t)4096 * 3072 * 2);  // 24 MB
  unsigned short* Vt    = (unsigned short*)alloc((size_t)32 * 64 * 2048 * 2); // 8 MB
  float* spart          = (float*)alloc((size_t)4 * 65536 * 4);             // 1 MB
  float* rsum           = (float*)alloc((size_t)65536 * 4);                 // 256 KB
  unsigned short* z1    = (unsigned short*)alloc((size_t)4096 * 1024 * 2);  // 8 MB
  // aliases onto dead regions:
  unsigned short* z2  = Vt;    // Vt dead after attn_pv
  unsigned short* z2n = xb;    // xb dead after QKV gemm
  unsigned short* z3  = QKV;   // QKV dead after attn_pv

  detect_dtype<<<1, 256, 0, stream>>>((const unsigned int*)x, flag);
  cvt_x<<<2048, 256, 0, stream>>>(x, xb, flag);

  w_transpose<<<dim3(16, 16), 256, 0, stream>>>(Wq, WTqkv, flag);
  w_transpose<<<dim3(16, 16), 256, 0, stream>>>(Wk, WTqkv + (size_t)1024 * 1024, flag);
  w_transpose<<<dim3(16, 16), 256, 0, stream>>>(Wv, WTqkv + (size_t)2048 * 1024, flag);
  w_transpose<<<dim3(16, 16), 256, 0, stream>>>(Wo, WoT, flag);
  w_transpose<<<dim3(16, 16), 256, 0, stream>>>(Wff, WffT, flag);

  // fused QKV projection: [4096,1024]@[1024,3072] -> QKV [4096,3072]
  gemm_bt_128x64<<<dim3(32, 48), 256, 0, stream>>>(xb, WTqkv, QKV,
                                                   4096, 3072, 1024, 1024, 1024, 3072);
  v_transpose<<<dim3(32, 32), 256, 0, stream>>>(QKV, Vt);
  attn_stats<<<dim3(32, 16, 4), 256, 0, stream>>>(QKV, spart);
  stats_combine<<<256, 256, 0, stream>>>(spart, rsum);
  attn_pv<<<dim3(32, 32), 256, 0, stream>>>(QKV, Vt, rsum, z1);

  gemm_bt_128x64<<<dim3(32, 16), 256, 0, stream>>>(z1, WoT, z2,
                                                   4096, 1024, 1024, 1024, 1024, 1024);
  l2norm_gelu<<<4096, 256, 0, stream>>>(z2, z2n, 0, 0, flag);
  gemm_bt_128x64<<<dim3(32, 16), 256, 0, stream>>>(z2n, WffT, z3,
                                                   4096, 1024, 1024, 1024, 1024, 1024);
  l2norm_gelu<<<4096, 256, 0, stream>>>(z3, d_out, 1, 1, flag);
}

// Round 5
// 300.836 us; speedup vs baseline: 1.3445x; 1.0715x over previous
//
#include <hip/hip_runtime.h>
#include <hip/hip_bf16.h>
#include <stdint.h>

// ---------------------------------------------------------------------------
// DecoderOnlyTransformer: x@Wq/Wk/Wv -> transposed-softmax attention -> @Wo
//   -> l2norm -> @Wff -> l2norm -> gelu(exact).  fp32 accum, bf16 MFMA core.
// B=2 S=2048 D=L=1024 H=16 dh=64.  Inputs fp32 (auto-detected fallback).
// Softmax over the QUERY axis (reference quirk); |scores| < 1 so the max
// subtraction is dropped (mathematically identical).
// Q is pre-scaled by 0.03125*log2(e) in the QKV GEMM epilogue so the score
// exponential is a bare exp2; V rows are pre-scaled by r_k = 1/sum_q exp(S).
// ---------------------------------------------------------------------------

typedef __attribute__((ext_vector_type(8))) short short8;   // 8 x bf16 (4 VGPRs)
typedef __attribute__((ext_vector_type(4))) float floatx4;  // MFMA accumulator

#define MFMA_BF16(a, b, c) __builtin_amdgcn_mfma_f32_16x16x32_bf16((a), (b), (c), 0, 0, 0)

#if defined(__has_builtin)
#if __has_builtin(__builtin_amdgcn_exp2f)
#define EXP2F(x) __builtin_amdgcn_exp2f(x)
#endif
#endif
#ifndef EXP2F
#define EXP2F(x) __expf((x) * 0.69314718056f)
#endif

__device__ __forceinline__ float bf2f(unsigned short u) {
  union { unsigned int i; float f; } v; v.i = ((unsigned int)u) << 16; return v.f;
}
__device__ __forceinline__ unsigned short f2bf(float f) {
  __hip_bfloat16 h = __float2bfloat16(f);
  return *reinterpret_cast<unsigned short*>(&h);
}
// async global->LDS, 16B per lane; lds dest is wave-uniform base + lane*16
__device__ __forceinline__ void gld_lds16(const void* g, void* l) {
  __builtin_amdgcn_global_load_lds((__attribute__((address_space(1))) void*)g,
                                   (__attribute__((address_space(3))) void*)l,
                                   16, 0, 0);
}

// ---------------------------------------------------------------------------
// Dtype sniffing: flag=1 -> bf16 inputs; flag=0 -> f32 inputs.
// ---------------------------------------------------------------------------
__global__ __launch_bounds__(256) void detect_dtype(const unsigned int* __restrict__ x,
                                                    int* __restrict__ flag)
{
  __shared__ int red[4];
  int ok = 0;
  for (int i = 0; i < 16; ++i) {
    const unsigned int w = x[threadIdx.x * 16 + i];
    const unsigned int e = (w >> 7) & 0xFF;
    ok += (e == 0 || (e >= 96 && e <= 144)) ? 1 : 0;
  }
  for (int off = 32; off > 0; off >>= 1) ok += __shfl_down(ok, off, 64);
  if ((threadIdx.x & 63) == 0) red[threadIdx.x >> 6] = ok;
  __syncthreads();
  if (threadIdx.x == 0)
    *flag = ((red[0] + red[1] + red[2] + red[3]) > 2048) ? 1 : 0;
}

// x -> canonical bf16 (8 elements/thread, 4096*1024 total)
__global__ __launch_bounds__(256) void cvt_x(const void* __restrict__ src,
                                             unsigned short* __restrict__ dst,
                                             const int* __restrict__ flag)
{
  const int i = blockIdx.x * 256 + threadIdx.x;
  if (*flag) {
    ((uint4*)dst)[i] = ((const uint4*)src)[i];
  } else {
    const float4 a = ((const float4*)src)[2 * i];
    const float4 b = ((const float4*)src)[2 * i + 1];
    unsigned short o[8] = {f2bf(a.x), f2bf(a.y), f2bf(a.z), f2bf(a.w),
                           f2bf(b.x), f2bf(b.y), f2bf(b.z), f2bf(b.w)};
    ((uint4*)dst)[i] = *(uint4*)o;
  }
}

// ---------------------------------------------------------------------------
// Generic C[M,N] = A[M,K] @ Bt[N,K]^T, bf16 in/out, fp32 accum.
// Tile 128x64, BK=32, 4 waves.  Columns < qscale_cols are scaled by
// 0.03125*log2(e) on output (used to pre-scale Q in the QKV projection).
// ---------------------------------------------------------------------------
__global__ __launch_bounds__(256) void gemm_bt_128x64(
    const unsigned short* __restrict__ A, const unsigned short* __restrict__ Bt,
    unsigned short* __restrict__ C, int M, int N, int K, int lda, int ldb, int ldc,
    int qscale_cols)
{
  __shared__ __align__(16) unsigned short sA[128 * 32];
  __shared__ __align__(16) unsigned short sB[64 * 32];
  const int tid = threadIdx.x;
  const int wave = tid >> 6, lane = tid & 63, l15 = lane & 15, quad = lane >> 4;
  const int m0 = blockIdx.x * 128, n0 = blockIdx.y * 64;

  const floatx4 z4 = {0.f, 0.f, 0.f, 0.f};
  floatx4 acc[2][4];
  for (int i = 0; i < 2; ++i) for (int j = 0; j < 4; ++j) acc[i][j] = z4;

  const int NK = K >> 5;
  auto stage = [&](int kt) {
    const int k0 = kt << 5;
    for (int j = 0; j < 2; ++j) {
      const int ci = j * 256 + wave * 64 + lane;
      gld_lds16(A + (size_t)(m0 + (ci >> 2)) * lda + k0 + (ci & 3) * 8,
                &sA[(j * 256 + wave * 64) * 8]);
    }
    {
      const int ci = wave * 64 + lane;
      gld_lds16(Bt + (size_t)(n0 + (ci >> 2)) * ldb + k0 + (ci & 3) * 8,
                &sB[(wave * 64) * 8]);
    }
  };

  stage(0);
  for (int kt = 0; kt < NK; ++kt) {
    __syncthreads();
    short8 af[2], bf[4];
    for (int mt = 0; mt < 2; ++mt)
      af[mt] = *(const short8*)&sA[(wave * 32 + mt * 16 + l15) * 32 + quad * 8];
    for (int nt = 0; nt < 4; ++nt)
      bf[nt] = *(const short8*)&sB[(nt * 16 + l15) * 32 + quad * 8];
    for (int mt = 0; mt < 2; ++mt)
      for (int nt = 0; nt < 4; ++nt)
        acc[mt][nt] = MFMA_BF16(af[mt], bf[nt], acc[mt][nt]);
    __syncthreads();
    if (kt + 1 < NK) stage(kt + 1);
  }
  for (int mt = 0; mt < 2; ++mt)
    for (int nt = 0; nt < 4; ++nt)
      for (int r = 0; r < 4; ++r) {
        const int row = m0 + wave * 32 + mt * 16 + quad * 4 + r;
        const int col = n0 + nt * 16 + l15;
        float v = acc[mt][nt][r];
        if (col < qscale_cols) v *= 0.04508422f;   // 0.03125 * log2(e)
        C[(size_t)row * ldc + col] = f2bf(v);
      }
}

// ---------------------------------------------------------------------------
// Fused 5x weight transpose (+dtype convert): WT[z][c][r] = W_z[r][c]
// grid (16,16,5)
// ---------------------------------------------------------------------------
__global__ __launch_bounds__(256) void w_transpose5(
    const void* __restrict__ W0, const void* __restrict__ W1,
    const void* __restrict__ W2, const void* __restrict__ W3,
    const void* __restrict__ W4, unsigned short* __restrict__ WT,
    const int* __restrict__ flag)
{
  __shared__ __align__(16) unsigned short tile[64 * 72];
  const void* srcs[5] = {W0, W1, W2, W3, W4};
  const void* W = srcs[blockIdx.z];
  unsigned short* dst0 = WT + (size_t)blockIdx.z * 1024 * 1024;
  const int rb = blockIdx.x * 64, cb = blockIdx.y * 64;
  const int tid = threadIdx.x;
  const int r = tid >> 2, c = tid & 3;
  unsigned short tmp[16];
  if (*flag) {
    const unsigned short* src = (const unsigned short*)W + (size_t)(rb + r) * 1024 + cb + c * 16;
    *(uint4*)&tmp[0] = *(const uint4*)src;
    *(uint4*)&tmp[8] = *(const uint4*)(src + 8);
  } else {
    const float* src = (const float*)W + (size_t)(rb + r) * 1024 + cb + c * 16;
    for (int j = 0; j < 16; j += 4) {
      const float4 f = *(const float4*)(src + j);
      tmp[j + 0] = f2bf(f.x); tmp[j + 1] = f2bf(f.y);
      tmp[j + 2] = f2bf(f.z); tmp[j + 3] = f2bf(f.w);
    }
  }
  *(uint4*)&tile[r * 72 + c * 16] = *(uint4*)&tmp[0];
  *(uint4*)&tile[r * 72 + c * 16 + 8] = *(uint4*)&tmp[8];
  __syncthreads();
  const int oc = tid >> 2;
  unsigned short out[16];
  for (int j = 0; j < 16; ++j) out[j] = tile[(c * 16 + j) * 72 + oc];
  unsigned short* dst = dst0 + (size_t)(cb + oc) * 1024 + rb + c * 16;
  *(uint4*)dst = *(uint4*)&out[0];
  *(uint4*)(dst + 8) = *(uint4*)&out[8];
}

// ---------------------------------------------------------------------------
// V-transpose + r_k scaling: Vt[bh][d][s] = rsum[bh][s] * V[b, s, h*64+d]
// ---------------------------------------------------------------------------
__global__ __launch_bounds__(256) void v_transpose(const unsigned short* __restrict__ QKV,
                                                   const float* __restrict__ rsum,
                                                   unsigned short* __restrict__ Vt)
{
  __shared__ __align__(16) unsigned short tile[64 * 72];
  const int bh = blockIdx.x, st = blockIdx.y;
  const int b = bh >> 4, h = bh & 15;
  const int tid = threadIdx.x;
  const int r = tid >> 2, c = tid & 3;
  const unsigned short* src =
      QKV + (size_t)(b * 2048 + st * 64 + r) * 3072 + 2048 + h * 64 + c * 16;
  *(uint4*)&tile[r * 72 + c * 16] = *(const uint4*)src;
  *(uint4*)&tile[r * 72 + c * 16 + 8] = *(const uint4*)(src + 8);
  __syncthreads();
  const int d = tid >> 2;
  const float* rsB = rsum + bh * 2048 + st * 64 + c * 16;
  unsigned short out[16];
  for (int j = 0; j < 16; ++j)
    out[j] = f2bf(bf2f(tile[(c * 16 + j) * 72 + d]) * rsB[j]);
  unsigned short* dst = Vt + (size_t)bh * 64 * 2048 + (size_t)d * 2048 + st * 64 + c * 16;
  *(uint4*)dst = *(uint4*)&out[0];
  *(uint4*)(dst + 8) = *(uint4*)&out[8];
}

// ---------------------------------------------------------------------------
// Attention stats: spart[qs][bh][k] = sum_{q in 512-quarter} exp2(<K,Q'>)
// (Q' pre-scaled).  Q-tiles staged fragment-major via global_load_lds,
// double-buffered, 1 barrier/tile.  grid (32 bh, 16 kb, 4 qs).
// ---------------------------------------------------------------------------
__global__ __launch_bounds__(256) void attn_stats(const unsigned short* __restrict__ QKV,
                                                  float* __restrict__ spart)
{
  __shared__ __align__(16) unsigned short sQ[2][8 * 512];
  const int bh = blockIdx.x, kb = blockIdx.y, qs = blockIdx.z;
  const int b = bh >> 4, h = bh & 15;
  const int tid = threadIdx.x;
  const int wave = tid >> 6, lane = tid & 63, l15 = lane & 15, quad = lane >> 4;
  const int kbase = kb * 128 + wave * 32;
  const size_t row0 = (size_t)b * 2048;
  const int qoff = h * 64, koff = 1024 + h * 64;
  const int qbase = qs * 512;

  short8 kf[2][2];
  for (int rt = 0; rt < 2; ++rt)
    for (int ks = 0; ks < 2; ++ks)
      kf[rt][ks] = *(const short8*)&QKV[(row0 + kbase + rt * 16 + l15) * 3072 +
                                        koff + ks * 32 + quad * 8];

  float l[2][4];
  for (int rt = 0; rt < 2; ++rt)
    for (int r = 0; r < 4; ++r) l[rt][r] = 0.f;

  auto stageQ = [&](int t) {
    const int qt0 = qbase + t * 64;
    for (int j = 0; j < 2; ++j) {
      const int f = wave * 2 + j;
      const int nt = f >> 1, ks = f & 1;
      gld_lds16(QKV + (row0 + qt0 + nt * 16 + l15) * 3072 + qoff + ks * 32 + quad * 8,
                &sQ[t & 1][f * 512]);
    }
  };

  const floatx4 z4 = {0.f, 0.f, 0.f, 0.f};
  stageQ(0);
  for (int t = 0; t < 8; ++t) {
    __syncthreads();
    if (t + 1 < 8) stageQ(t + 1);
    const unsigned short* sQt = sQ[t & 1];
    for (int nt = 0; nt < 4; ++nt) {
      const short8 bq0 = *(const short8*)&sQt[(nt * 2 + 0) * 512 + lane * 8];
      const short8 bq1 = *(const short8*)&sQt[(nt * 2 + 1) * 512 + lane * 8];
      for (int rt = 0; rt < 2; ++rt) {
        floatx4 acc = z4;
        acc = MFMA_BF16(kf[rt][0], bq0, acc);
        acc = MFMA_BF16(kf[rt][1], bq1, acc);
        for (int r = 0; r < 4; ++r)
          l[rt][r] += EXP2F(acc[r]);
      }
    }
  }
  for (int rt = 0; rt < 2; ++rt)
    for (int r = 0; r < 4; ++r) {
      float ll = l[rt][r];
      ll += __shfl_xor(ll, 1, 64);
      ll += __shfl_xor(ll, 2, 64);
      ll += __shfl_xor(ll, 4, 64);
      ll += __shfl_xor(ll, 8, 64);
      if (l15 == 0) {
        const int krow = kbase + rt * 16 + quad * 4 + r;
        spart[(size_t)qs * 65536 + bh * 2048 + krow] = ll;
      }
    }
}

// rsum = 1 / (sum of 4 q-quarter partials), 65536 elements
__global__ __launch_bounds__(256) void stats_combine(const float* __restrict__ spart,
                                                     float* __restrict__ rsum)
{
  const int i = blockIdx.x * 256 + threadIdx.x;
  rsum[i] = 1.0f / (spart[i] + spart[i + 65536] + spart[i + 131072] + spart[i + 196608]);
}

// ---------------------------------------------------------------------------
// Attention PV: Out[q,d] = sum_k exp2(<Q'_q,K_k>) * V'[k,d]   (V' = r_k*V)
// grid (32 bh, 32 qb of 64); k-tiles of 64, K/V double-buffered in LDS,
// ONE barrier per k-tile.  P computed in two 32-k halves through a small
// wave-local LDS buffer (no barrier needed for the C->A layout round-trip).
// 4 waves x 16 q-rows.  LDS: 2*8K + 2*8K + 4.5K = 37.4 KB -> 4 blocks/CU.
// ---------------------------------------------------------------------------
__global__ __launch_bounds__(256) void attn_pv(const unsigned short* __restrict__ QKV,
                                               const unsigned short* __restrict__ Vt,
                                               unsigned short* __restrict__ Z1)
{
  __shared__ __align__(16) unsigned short sK[2][64 * 64];  // [k-row][dh]
  __shared__ __align__(16) unsigned short sV[2][64 * 64];  // [d][k]
  __shared__ __align__(16) unsigned short sP[64 * 36];     // [q][k-half] wave-local rows
  const int bh = blockIdx.x, qb = blockIdx.y;
  const int b = bh >> 4, h = bh & 15;
  const int tid = threadIdx.x;
  const int wave = tid >> 6, lane = tid & 63, l15 = lane & 15, quad = lane >> 4;
  const size_t row0 = (size_t)b * 2048;
  const int qoff = h * 64, koff = 1024 + h * 64;
  const int q0 = qb * 64;
  const int srow = lane >> 3, schk = (lane & 7) ^ ((lane >> 3) & 7);

  short8 qf[2];  // A-operand Q' frags for this wave's 16 q-rows
  for (int ks = 0; ks < 2; ++ks)
    qf[ks] = *(const short8*)&QKV[(row0 + q0 + wave * 16 + l15) * 3072 +
                                  qoff + ks * 32 + quad * 8];

  const floatx4 z4 = {0.f, 0.f, 0.f, 0.f};
  floatx4 acco[4];
  for (int j = 0; j < 4; ++j) acco[j] = z4;

  const unsigned short* VtB = Vt + (size_t)bh * 64 * 2048;

  auto stage = [&](int kt) {
    const int kb = kt * 64;
    const int bufi = kt & 1;
    for (int j = 0; j < 2; ++j) {
      const int jj = wave * 2 + j;  // 8-row group
      gld_lds16(QKV + (row0 + kb + jj * 8 + srow) * 3072 + koff + schk * 8,
                &sK[bufi][jj * 512]);
      gld_lds16(VtB + (size_t)(jj * 8 + srow) * 2048 + kb + schk * 8,
                &sV[bufi][jj * 512]);
    }
  };

  stage(0);
  for (int kt = 0; kt < 32; ++kt) {
    __syncthreads();                 // stage(kt) landed; prev readers of buf done
    if (kt + 1 < 32) stage(kt + 1);  // prefetch into other buffer (drains at next barrier)
    const unsigned short* sKt = sK[kt & 1];
    const unsigned short* sVt = sV[kt & 1];
    for (int h2 = 0; h2 < 2; ++h2) {           // 32-k half
      // --- S^T: rows q (wave's 16), cols k in [h2*32, h2*32+32) ---
      floatx4 sacc[2];
      for (int nt2 = 0; nt2 < 2; ++nt2) {
        floatx4 a = z4;
        for (int ks = 0; ks < 2; ++ks) {
          const int row = h2 * 32 + nt2 * 16 + l15;          // k index
          const int chk = (ks * 4 + quad) ^ (l15 & 7);       // swizzled dh-chunk
          a = MFMA_BF16(qf[ks], *(const short8*)&sKt[row * 64 + chk * 8], a);
        }
        sacc[nt2] = a;
      }
      // --- P~ = exp2(S) -> wave-local LDS rows (C-layout -> A-layout) ---
      for (int nt2 = 0; nt2 < 2; ++nt2)
        for (int r = 0; r < 4; ++r)
          sP[(wave * 16 + quad * 4 + r) * 36 + nt2 * 16 + l15] = f2bf(EXP2F(sacc[nt2][r]));
      // (no barrier: each wave reads back only its own rows)
      const short8 pf = *(const short8*)&sP[(wave * 16 + l15) * 36 + quad * 8];
      // --- Out += P~ @ V' for this k half ---
      for (int nt = 0; nt < 4; ++nt) {
        const int row = nt * 16 + l15;                       // d index
        const int chk = (h2 * 4 + quad) ^ (l15 & 7);         // swizzled k-chunk
        acco[nt] = MFMA_BF16(pf, *(const short8*)&sVt[row * 64 + chk * 8], acco[nt]);
      }
    }
  }
  for (int nt = 0; nt < 4; ++nt)
    for (int r = 0; r < 4; ++r) {
      const int q = q0 + wave * 16 + quad * 4 + r;
      const int d = nt * 16 + l15;
      Z1[(row0 + q) * 1024 + qoff + d] = f2bf(acco[nt][r]);
    }
}

// ---------------------------------------------------------------------------
// Row-wise L2 normalize (1024 cols), optional exact-erf GELU.  1 block/row.
// ---------------------------------------------------------------------------
__global__ __launch_bounds__(256) void l2norm_gelu(const unsigned short* __restrict__ in,
                                                   void* __restrict__ out, int do_gelu,
                                                   int fin, const int* __restrict__ flag)
{
  __shared__ float red[4];
  const int row = blockIdx.x, tid = threadIdx.x;
  const unsigned short* p = in + (size_t)row * 1024 + tid * 4;
  const ushort4 u = *(const ushort4*)p;
  float x[4] = {bf2f(u.x), bf2f(u.y), bf2f(u.z), bf2f(u.w)};
  float ss = x[0] * x[0] + x[1] * x[1] + x[2] * x[2] + x[3] * x[3];
  for (int off = 32; off > 0; off >>= 1) ss += __shfl_down(ss, off, 64);
  if ((tid & 63) == 0) red[tid >> 6] = ss;
  __syncthreads();
  const float tot = red[0] + red[1] + red[2] + red[3];
  const float sc = 1.0f / fmaxf(sqrtf(tot), 1e-12f);
  float y[4];
  for (int j = 0; j < 4; ++j) {
    y[j] = x[j] * sc;
    if (do_gelu) y[j] = 0.5f * y[j] * (1.0f + erff(y[j] * 0.70710678118654752f));
  }
  if (fin && *flag == 0) {
    float4 o = {y[0], y[1], y[2], y[3]};
    ((float4*)out)[(size_t)row * 256 + tid] = o;
  } else {
    ushort4 o = {f2bf(y[0]), f2bf(y[1]), f2bf(y[2]), f2bf(y[3])};
    ((ushort4*)out)[(size_t)row * 256 + tid] = o;
  }
}

// ---------------------------------------------------------------------------
extern "C" void kernel_launch(void* const* d_in, const int* in_sizes, int n_in,
                              void* d_out, int out_size, void* d_ws, size_t ws_size,
                              hipStream_t stream)
{
  const void* x   = d_in[0];
  const void* Wq  = d_in[1];
  const void* Wk  = d_in[2];
  const void* Wv  = d_in[3];
  const void* Wo  = d_in[4];
  const void* Wff = d_in[5];

  char* ws = (char*)d_ws;
  size_t off = 0;
  auto alloc = [&](size_t bytes) -> void* {
    void* p = ws + off; off += (bytes + 255) & ~(size_t)255; return p;
  };
  int* flag             = (int*)alloc(256);
  unsigned short* xb    = (unsigned short*)alloc((size_t)4096 * 1024 * 2);  // 8 MB
  unsigned short* WT    = (unsigned short*)alloc((size_t)5 * 1024 * 1024 * 2); // 10 MB: Wq,Wk,Wv,Wo,Wff
  unsigned short* QKV   = (unsigned short*)alloc((size_t)4096 * 3072 * 2);  // 24 MB
  unsigned short* Vt    = (unsigned short*)alloc((size_t)32 * 64 * 2048 * 2); // 8 MB
  float* spart          = (float*)alloc((size_t)4 * 65536 * 4);             // 1 MB
  float* rsum           = (float*)alloc((size_t)65536 * 4);                 // 256 KB
  unsigned short* z1    = (unsigned short*)alloc((size_t)4096 * 1024 * 2);  // 8 MB
  unsigned short* WTqkv = WT;                          // slots 0..2
  unsigned short* WoT   = WT + (size_t)3 * 1024 * 1024;
  unsigned short* WffT  = WT + (size_t)4 * 1024 * 1024;
  // aliases onto dead regions:
  unsigned short* z2  = Vt;    // Vt dead after attn_pv
  unsigned short* z2n = xb;    // xb dead after QKV gemm
  unsigned short* z3  = QKV;   // QKV dead after attn_pv

  detect_dtype<<<1, 256, 0, stream>>>((const unsigned int*)x, flag);
  cvt_x<<<2048, 256, 0, stream>>>(x, xb, flag);
  w_transpose5<<<dim3(16, 16, 5), 256, 0, stream>>>(Wq, Wk, Wv, Wo, Wff, WT, flag);

  // fused QKV projection (Q columns pre-scaled by 0.03125*log2e)
  gemm_bt_128x64<<<dim3(32, 48), 256, 0, stream>>>(xb, WTqkv, QKV,
                                                   4096, 3072, 1024, 1024, 1024, 3072, 1024);
  attn_stats<<<dim3(32, 16, 4), 256, 0, stream>>>(QKV, spart);
  stats_combine<<<256, 256, 0, stream>>>(spart, rsum);
  v_transpose<<<dim3(32, 32), 256, 0, stream>>>(QKV, rsum, Vt);
  attn_pv<<<dim3(32, 32), 256, 0, stream>>>(QKV, Vt, z1);

  gemm_bt_128x64<<<dim3(32, 16), 256, 0, stream>>>(z1, WoT, z2,
                                                   4096, 1024, 1024, 1024, 1024, 1024, 0);
  l2norm_gelu<<<4096, 256, 0, stream>>>(z2, z2n, 0, 0, flag);
  gemm_bt_128x64<<<dim3(32, 16), 256, 0, stream>>>(z2n, WffT, z3,
                                                   4096, 1024, 1024, 1024, 1024, 1024, 0);
  l2norm_gelu<<<4096, 256, 0, stream>>>(z3, d_out, 1, 1, flag);
}

// Round 6
// 298.029 us; speedup vs baseline: 1.3572x; 1.0094x over previous
//
#include <hip/hip_runtime.h>
#include <hip/hip_bf16.h>
#include <stdint.h>

// ---------------------------------------------------------------------------
// DecoderOnlyTransformer: x@Wq/Wk/Wv -> transposed-softmax attention -> @Wo
//   -> l2norm -> @Wff -> l2norm -> gelu(exact).  fp32 accum, bf16 MFMA core.
// B=2 S=2048 D=L=1024 H=16 dh=64.  Inputs fp32 (auto-detected fallback).
// Softmax over the QUERY axis (reference quirk); |scores| < 1 so the max
// subtraction is dropped (mathematically identical).
// Q pre-scaled by 0.03125*log2(e) in the QKV epilogue -> score exp is exp2;
// V rows pre-scaled by r_k = 1/sum_q exp(S).
// attn_pv is LDS-issue-bound -> 32 q-rows per wave so each LDS B-fragment
// read feeds 2 MFMAs (round-5 profile: 70 us ~= pure LDS-issue time).
// ---------------------------------------------------------------------------

typedef __attribute__((ext_vector_type(8))) short short8;   // 8 x bf16 (4 VGPRs)
typedef __attribute__((ext_vector_type(4))) float floatx4;  // MFMA accumulator

#define MFMA_BF16(a, b, c) __builtin_amdgcn_mfma_f32_16x16x32_bf16((a), (b), (c), 0, 0, 0)

#if defined(__has_builtin)
#if __has_builtin(__builtin_amdgcn_exp2f)
#define EXP2F(x) __builtin_amdgcn_exp2f(x)
#endif
#endif
#ifndef EXP2F
#define EXP2F(x) __expf((x) * 0.69314718056f)
#endif

__device__ __forceinline__ float bf2f(unsigned short u) {
  union { unsigned int i; float f; } v; v.i = ((unsigned int)u) << 16; return v.f;
}
__device__ __forceinline__ unsigned short f2bf(float f) {
  __hip_bfloat16 h = __float2bfloat16(f);
  return *reinterpret_cast<unsigned short*>(&h);
}
// async global->LDS, 16B per lane; lds dest is wave-uniform base + lane*16
__device__ __forceinline__ void gld_lds16(const void* g, void* l) {
  __builtin_amdgcn_global_load_lds((__attribute__((address_space(1))) void*)g,
                                   (__attribute__((address_space(3))) void*)l,
                                   16, 0, 0);
}

// ---------------------------------------------------------------------------
// Dtype sniffing: flag=1 -> bf16 inputs; flag=0 -> f32 inputs.
// ---------------------------------------------------------------------------
__global__ __launch_bounds__(256) void detect_dtype(const unsigned int* __restrict__ x,
                                                    int* __restrict__ flag)
{
  __shared__ int red[4];
  int ok = 0;
  for (int i = 0; i < 16; ++i) {
    const unsigned int w = x[threadIdx.x * 16 + i];
    const unsigned int e = (w >> 7) & 0xFF;
    ok += (e == 0 || (e >= 96 && e <= 144)) ? 1 : 0;
  }
  for (int off = 32; off > 0; off >>= 1) ok += __shfl_down(ok, off, 64);
  if ((threadIdx.x & 63) == 0) red[threadIdx.x >> 6] = ok;
  __syncthreads();
  if (threadIdx.x == 0)
    *flag = ((red[0] + red[1] + red[2] + red[3]) > 2048) ? 1 : 0;
}

// x -> canonical bf16 (8 elements/thread, 4096*1024 total)
__global__ __launch_bounds__(256) void cvt_x(const void* __restrict__ src,
                                             unsigned short* __restrict__ dst,
                                             const int* __restrict__ flag)
{
  const int i = blockIdx.x * 256 + threadIdx.x;
  if (*flag) {
    ((uint4*)dst)[i] = ((const uint4*)src)[i];
  } else {
    const float4 a = ((const float4*)src)[2 * i];
    const float4 b = ((const float4*)src)[2 * i + 1];
    unsigned short o[8] = {f2bf(a.x), f2bf(a.y), f2bf(a.z), f2bf(a.w),
                           f2bf(b.x), f2bf(b.y), f2bf(b.z), f2bf(b.w)};
    ((uint4*)dst)[i] = *(uint4*)o;
  }
}

// ---------------------------------------------------------------------------
// C[M,N] = A[M,K] @ Bt[N,K]^T, bf16 in/out, fp32 accum.  Tile 128x64, BK=32.
// Columns < qscale_cols scaled by 0.03125*log2(e) on output.
// ---------------------------------------------------------------------------
__global__ __launch_bounds__(256) void gemm_bt_128x64(
    const unsigned short* __restrict__ A, const unsigned short* __restrict__ Bt,
    unsigned short* __restrict__ C, int M, int N, int K, int lda, int ldb, int ldc,
    int qscale_cols)
{
  __shared__ __align__(16) unsigned short sA[128 * 32];
  __shared__ __align__(16) unsigned short sB[64 * 32];
  const int tid = threadIdx.x;
  const int wave = tid >> 6, lane = tid & 63, l15 = lane & 15, quad = lane >> 4;
  const int m0 = blockIdx.x * 128, n0 = blockIdx.y * 64;

  const floatx4 z4 = {0.f, 0.f, 0.f, 0.f};
  floatx4 acc[2][4];
  for (int i = 0; i < 2; ++i) for (int j = 0; j < 4; ++j) acc[i][j] = z4;

  const int NK = K >> 5;
  auto stage = [&](int kt) {
    const int k0 = kt << 5;
    for (int j = 0; j < 2; ++j) {
      const int ci = j * 256 + wave * 64 + lane;
      gld_lds16(A + (size_t)(m0 + (ci >> 2)) * lda + k0 + (ci & 3) * 8,
                &sA[(j * 256 + wave * 64) * 8]);
    }
    {
      const int ci = wave * 64 + lane;
      gld_lds16(Bt + (size_t)(n0 + (ci >> 2)) * ldb + k0 + (ci & 3) * 8,
                &sB[(wave * 64) * 8]);
    }
  };

  stage(0);
  for (int kt = 0; kt < NK; ++kt) {
    __syncthreads();
    short8 af[2], bf[4];
    for (int mt = 0; mt < 2; ++mt)
      af[mt] = *(const short8*)&sA[(wave * 32 + mt * 16 + l15) * 32 + quad * 8];
    for (int nt = 0; nt < 4; ++nt)
      bf[nt] = *(const short8*)&sB[(nt * 16 + l15) * 32 + quad * 8];
    for (int mt = 0; mt < 2; ++mt)
      for (int nt = 0; nt < 4; ++nt)
        acc[mt][nt] = MFMA_BF16(af[mt], bf[nt], acc[mt][nt]);
    __syncthreads();
    if (kt + 1 < NK) stage(kt + 1);
  }
  for (int mt = 0; mt < 2; ++mt)
    for (int nt = 0; nt < 4; ++nt)
      for (int r = 0; r < 4; ++r) {
        const int row = m0 + wave * 32 + mt * 16 + quad * 4 + r;
        const int col = n0 + nt * 16 + l15;
        float v = acc[mt][nt][r];
        if (col < qscale_cols) v *= 0.04508422f;   // 0.03125 * log2(e)
        C[(size_t)row * ldc + col] = f2bf(v);
      }
}

// ---------------------------------------------------------------------------
// C[M,N] = A[M,K] @ Bt[N,K]^T, tile 128x128 (m97 shape), BK=32, 2x2 waves.
// Each b128 LDS read feeds 4 MFMAs.  Used for the big QKV projection.
// ---------------------------------------------------------------------------
__global__ __launch_bounds__(256) void gemm_bt_128x128(
    const unsigned short* __restrict__ A, const unsigned short* __restrict__ Bt,
    unsigned short* __restrict__ C, int M, int N, int K, int lda, int ldb, int ldc,
    int qscale_cols)
{
  __shared__ __align__(16) unsigned short sA[128 * 32];
  __shared__ __align__(16) unsigned short sB[128 * 32];
  const int tid = threadIdx.x;
  const int wave = tid >> 6, lane = tid & 63, l15 = lane & 15, quad = lane >> 4;
  const int wr = wave >> 1, wc = wave & 1;
  const int m0 = blockIdx.x * 128, n0 = blockIdx.y * 128;

  const floatx4 z4 = {0.f, 0.f, 0.f, 0.f};
  floatx4 acc[4][4];
  for (int i = 0; i < 4; ++i) for (int j = 0; j < 4; ++j) acc[i][j] = z4;

  const int NK = K >> 5;
  auto stage = [&](int kt) {
    const int k0 = kt << 5;
    for (int j = 0; j < 2; ++j) {
      const int ci = j * 256 + wave * 64 + lane;
      gld_lds16(A + (size_t)(m0 + (ci >> 2)) * lda + k0 + (ci & 3) * 8,
                &sA[(j * 256 + wave * 64) * 8]);
      gld_lds16(Bt + (size_t)(n0 + (ci >> 2)) * ldb + k0 + (ci & 3) * 8,
                &sB[(j * 256 + wave * 64) * 8]);
    }
  };

  stage(0);
  for (int kt = 0; kt < NK; ++kt) {
    __syncthreads();
    short8 af[4], bf[4];
    for (int mt = 0; mt < 4; ++mt)
      af[mt] = *(const short8*)&sA[(wr * 64 + mt * 16 + l15) * 32 + quad * 8];
    for (int nt = 0; nt < 4; ++nt)
      bf[nt] = *(const short8*)&sB[(wc * 64 + nt * 16 + l15) * 32 + quad * 8];
    for (int mt = 0; mt < 4; ++mt)
      for (int nt = 0; nt < 4; ++nt)
        acc[mt][nt] = MFMA_BF16(af[mt], bf[nt], acc[mt][nt]);
    __syncthreads();
    if (kt + 1 < NK) stage(kt + 1);
  }
  for (int mt = 0; mt < 4; ++mt)
    for (int nt = 0; nt < 4; ++nt)
      for (int r = 0; r < 4; ++r) {
        const int row = m0 + wr * 64 + mt * 16 + quad * 4 + r;
        const int col = n0 + wc * 64 + nt * 16 + l15;
        float v = acc[mt][nt][r];
        if (col < qscale_cols) v *= 0.04508422f;   // 0.03125 * log2(e)
        C[(size_t)row * ldc + col] = f2bf(v);
      }
}

// ---------------------------------------------------------------------------
// Fused 5x weight transpose (+dtype convert): WT[z][c][r] = W_z[r][c]
// ---------------------------------------------------------------------------
__global__ __launch_bounds__(256) void w_transpose5(
    const void* __restrict__ W0, const void* __restrict__ W1,
    const void* __restrict__ W2, const void* __restrict__ W3,
    const void* __restrict__ W4, unsigned short* __restrict__ WT,
    const int* __restrict__ flag)
{
  __shared__ __align__(16) unsigned short tile[64 * 72];
  const void* srcs[5] = {W0, W1, W2, W3, W4};
  const void* W = srcs[blockIdx.z];
  unsigned short* dst0 = WT + (size_t)blockIdx.z * 1024 * 1024;
  const int rb = blockIdx.x * 64, cb = blockIdx.y * 64;
  const int tid = threadIdx.x;
  const int r = tid >> 2, c = tid & 3;
  unsigned short tmp[16];
  if (*flag) {
    const unsigned short* src = (const unsigned short*)W + (size_t)(rb + r) * 1024 + cb + c * 16;
    *(uint4*)&tmp[0] = *(const uint4*)src;
    *(uint4*)&tmp[8] = *(const uint4*)(src + 8);
  } else {
    const float* src = (const float*)W + (size_t)(rb + r) * 1024 + cb + c * 16;
    for (int j = 0; j < 16; j += 4) {
      const float4 f = *(const float4*)(src + j);
      tmp[j + 0] = f2bf(f.x); tmp[j + 1] = f2bf(f.y);
      tmp[j + 2] = f2bf(f.z); tmp[j + 3] = f2bf(f.w);
    }
  }
  *(uint4*)&tile[r * 72 + c * 16] = *(uint4*)&tmp[0];
  *(uint4*)&tile[r * 72 + c * 16 + 8] = *(uint4*)&tmp[8];
  __syncthreads();
  const int oc = tid >> 2;
  unsigned short out[16];
  for (int j = 0; j < 16; ++j) out[j] = tile[(c * 16 + j) * 72 + oc];
  unsigned short* dst = dst0 + (size_t)(cb + oc) * 1024 + rb + c * 16;
  *(uint4*)dst = *(uint4*)&out[0];
  *(uint4*)(dst + 8) = *(uint4*)&out[8];
}

// ---------------------------------------------------------------------------
// V-transpose + r_k scaling: Vt[bh][d][s] = rsum[bh][s] * V[b, s, h*64+d]
// ---------------------------------------------------------------------------
__global__ __launch_bounds__(256) void v_transpose(const unsigned short* __restrict__ QKV,
                                                   const float* __restrict__ rsum,
                                                   unsigned short* __restrict__ Vt)
{
  __shared__ __align__(16) unsigned short tile[64 * 72];
  const int bh = blockIdx.x, st = blockIdx.y;
  const int b = bh >> 4, h = bh & 15;
  const int tid = threadIdx.x;
  const int r = tid >> 2, c = tid & 3;
  const unsigned short* src =
      QKV + (size_t)(b * 2048 + st * 64 + r) * 3072 + 2048 + h * 64 + c * 16;
  *(uint4*)&tile[r * 72 + c * 16] = *(const uint4*)src;
  *(uint4*)&tile[r * 72 + c * 16 + 8] = *(const uint4*)(src + 8);
  __syncthreads();
  const int d = tid >> 2;
  const float* rsB = rsum + bh * 2048 + st * 64 + c * 16;
  unsigned short out[16];
  for (int j = 0; j < 16; ++j)
    out[j] = f2bf(bf2f(tile[(c * 16 + j) * 72 + d]) * rsB[j]);
  unsigned short* dst = Vt + (size_t)bh * 64 * 2048 + (size_t)d * 2048 + st * 64 + c * 16;
  *(uint4*)dst = *(uint4*)&out[0];
  *(uint4*)(dst + 8) = *(uint4*)&out[8];
}

// ---------------------------------------------------------------------------
// Attention stats: spart[qs][bh][k] = sum_{q in 512-quarter} exp2(<K,Q'>)
// Q-tiles staged fragment-major via global_load_lds, double-buffered.
// grid (32 bh, 16 kb, 4 qs).
// ---------------------------------------------------------------------------
__global__ __launch_bounds__(256) void attn_stats(const unsigned short* __restrict__ QKV,
                                                  float* __restrict__ spart)
{
  __shared__ __align__(16) unsigned short sQ[2][8 * 512];
  const int bh = blockIdx.x, kb = blockIdx.y, qs = blockIdx.z;
  const int b = bh >> 4, h = bh & 15;
  const int tid = threadIdx.x;
  const int wave = tid >> 6, lane = tid & 63, l15 = lane & 15, quad = lane >> 4;
  const int kbase = kb * 128 + wave * 32;
  const size_t row0 = (size_t)b * 2048;
  const int qoff = h * 64, koff = 1024 + h * 64;
  const int qbase = qs * 512;

  short8 kf[2][2];
  for (int rt = 0; rt < 2; ++rt)
    for (int ks = 0; ks < 2; ++ks)
      kf[rt][ks] = *(const short8*)&QKV[(row0 + kbase + rt * 16 + l15) * 3072 +
                                        koff + ks * 32 + quad * 8];

  float l[2][4];
  for (int rt = 0; rt < 2; ++rt)
    for (int r = 0; r < 4; ++r) l[rt][r] = 0.f;

  auto stageQ = [&](int t) {
    const int qt0 = qbase + t * 64;
    for (int j = 0; j < 2; ++j) {
      const int f = wave * 2 + j;
      const int nt = f >> 1, ks = f & 1;
      gld_lds16(QKV + (row0 + qt0 + nt * 16 + l15) * 3072 + qoff + ks * 32 + quad * 8,
                &sQ[t & 1][f * 512]);
    }
  };

  const floatx4 z4 = {0.f, 0.f, 0.f, 0.f};
  stageQ(0);
  for (int t = 0; t < 8; ++t) {
    __syncthreads();
    if (t + 1 < 8) stageQ(t + 1);
    const unsigned short* sQt = sQ[t & 1];
    for (int nt = 0; nt < 4; ++nt) {
      const short8 bq0 = *(const short8*)&sQt[(nt * 2 + 0) * 512 + lane * 8];
      const short8 bq1 = *(const short8*)&sQt[(nt * 2 + 1) * 512 + lane * 8];
      for (int rt = 0; rt < 2; ++rt) {
        floatx4 acc = z4;
        acc = MFMA_BF16(kf[rt][0], bq0, acc);
        acc = MFMA_BF16(kf[rt][1], bq1, acc);
        for (int r = 0; r < 4; ++r)
          l[rt][r] += EXP2F(acc[r]);
      }
    }
  }
  for (int rt = 0; rt < 2; ++rt)
    for (int r = 0; r < 4; ++r) {
      float ll = l[rt][r];
      ll += __shfl_xor(ll, 1, 64);
      ll += __shfl_xor(ll, 2, 64);
      ll += __shfl_xor(ll, 4, 64);
      ll += __shfl_xor(ll, 8, 64);
      if (l15 == 0) {
        const int krow = kbase + rt * 16 + quad * 4 + r;
        spart[(size_t)qs * 65536 + bh * 2048 + krow] = ll;
      }
    }
}

// rsum = 1 / (sum of 4 q-quarter partials), 65536 elements
__global__ __launch_bounds__(256) void stats_combine(const float* __restrict__ spart,
                                                     float* __restrict__ rsum)
{
  const int i = blockIdx.x * 256 + threadIdx.x;
  rsum[i] = 1.0f / (spart[i] + spart[i + 65536] + spart[i + 131072] + spart[i + 196608]);
}

// ---------------------------------------------------------------------------
// Attention PV: Out[q,d] = sum_k exp2(<Q'_q,K_k>) * V'[k,d]   (V' = r_k*V)
// grid (32 bh, 16 qb of 128); 4 waves x 32 q-rows (2 A-frags each -> every
// LDS B-fragment read feeds 2 MFMAs).  k-tiles of 64 double-buffered, ONE
// barrier per k-tile; P via wave-local LDS rows (no barrier).
// LDS: 16K + 16K + 9K = 41 KB -> 2 blocks/CU (grid-limited).
// ---------------------------------------------------------------------------
__global__ __launch_bounds__(256) void attn_pv(const unsigned short* __restrict__ QKV,
                                               const unsigned short* __restrict__ Vt,
                                               unsigned short* __restrict__ Z1)
{
  __shared__ __align__(16) unsigned short sK[2][64 * 64];  // [k-row][dh]
  __shared__ __align__(16) unsigned short sV[2][64 * 64];  // [d][k]
  __shared__ __align__(16) unsigned short sP[128 * 36];    // [q][k-half] wave-local
  const int bh = blockIdx.x, qb = blockIdx.y;
  const int b = bh >> 4, h = bh & 15;
  const int tid = threadIdx.x;
  const int wave = tid >> 6, lane = tid & 63, l15 = lane & 15, quad = lane >> 4;
  const size_t row0 = (size_t)b * 2048;
  const int qoff = h * 64, koff = 1024 + h * 64;
  const int q0 = qb * 128;
  const int srow = lane >> 3, schk = (lane & 7) ^ ((lane >> 3) & 7);

  short8 qf[2][2];  // [mt][ks] A-operand Q' frags for this wave's 32 q-rows
  for (int mt = 0; mt < 2; ++mt)
    for (int ks = 0; ks < 2; ++ks)
      qf[mt][ks] = *(const short8*)&QKV[(row0 + q0 + wave * 32 + mt * 16 + l15) * 3072 +
                                        qoff + ks * 32 + quad * 8];

  const floatx4 z4 = {0.f, 0.f, 0.f, 0.f};
  floatx4 acco[2][4];  // [mt][nt]
  for (int i = 0; i < 2; ++i) for (int j = 0; j < 4; ++j) acco[i][j] = z4;

  const unsigned short* VtB = Vt + (size_t)bh * 64 * 2048;

  auto stage = [&](int kt) {
    const int kb = kt * 64;
    const int bufi = kt & 1;
    for (int j = 0; j < 2; ++j) {
      const int jj = wave * 2 + j;  // 8-row group
      gld_lds16(QKV + (row0 + kb + jj * 8 + srow) * 3072 + koff + schk * 8,
                &sK[bufi][jj * 512]);
      gld_lds16(VtB + (size_t)(jj * 8 + srow) * 2048 + kb + schk * 8,
                &sV[bufi][jj * 512]);
    }
  };

  stage(0);
  for (int kt = 0; kt < 32; ++kt) {
    __syncthreads();                 // stage(kt) landed; prev readers of buf done
    if (kt + 1 < 32) stage(kt + 1);  // prefetch into other buffer
    const unsigned short* sKt = sK[kt & 1];
    const unsigned short* sVt = sV[kt & 1];
    for (int h2 = 0; h2 < 2; ++h2) {           // 32-k half
      // --- S^T: rows q (wave's 32), cols k in [h2*32, h2*32+32) ---
      floatx4 sacc[2][2];  // [mt][nt2]
      sacc[0][0] = z4; sacc[0][1] = z4; sacc[1][0] = z4; sacc[1][1] = z4;
      for (int nt2 = 0; nt2 < 2; ++nt2)
        for (int ks = 0; ks < 2; ++ks) {
          const int row = h2 * 32 + nt2 * 16 + l15;          // k index
          const int chk = (ks * 4 + quad) ^ (l15 & 7);       // swizzled dh-chunk
          const short8 kfr = *(const short8*)&sKt[row * 64 + chk * 8];
          sacc[0][nt2] = MFMA_BF16(qf[0][ks], kfr, sacc[0][nt2]);
          sacc[1][nt2] = MFMA_BF16(qf[1][ks], kfr, sacc[1][nt2]);
        }
      // --- P~ = exp2(S) -> wave-local LDS rows (C-layout -> A-layout) ---
      for (int mt = 0; mt < 2; ++mt)
        for (int nt2 = 0; nt2 < 2; ++nt2)
          for (int r = 0; r < 4; ++r)
            sP[(wave * 32 + mt * 16 + quad * 4 + r) * 36 + nt2 * 16 + l15] =
                f2bf(EXP2F(sacc[mt][nt2][r]));
      // (no barrier: each wave reads back only its own rows)
      short8 pf[2];
      for (int mt = 0; mt < 2; ++mt)
        pf[mt] = *(const short8*)&sP[(wave * 32 + mt * 16 + l15) * 36 + quad * 8];
      // --- Out += P~ @ V' for this k half ---
      for (int nt = 0; nt < 4; ++nt) {
        const int row = nt * 16 + l15;                       // d index
        const int chk = (h2 * 4 + quad) ^ (l15 & 7);         // swizzled k-chunk
        const short8 vf = *(const short8*)&sVt[row * 64 + chk * 8];
        acco[0][nt] = MFMA_BF16(pf[0], vf, acco[0][nt]);
        acco[1][nt] = MFMA_BF16(pf[1], vf, acco[1][nt]);
      }
    }
  }
  for (int mt = 0; mt < 2; ++mt)
    for (int nt = 0; nt < 4; ++nt)
      for (int r = 0; r < 4; ++r) {
        const int q = q0 + wave * 32 + mt * 16 + quad * 4 + r;
        const int d = nt * 16 + l15;
        Z1[(row0 + q) * 1024 + qoff + d] = f2bf(acco[mt][nt][r]);
      }
}

// ---------------------------------------------------------------------------
// Row-wise L2 normalize (1024 cols), optional exact-erf GELU.  1 block/row.
// ---------------------------------------------------------------------------
__global__ __launch_bounds__(256) void l2norm_gelu(const unsigned short* __restrict__ in,
                                                   void* __restrict__ out, int do_gelu,
                                                   int fin, const int* __restrict__ flag)
{
  __shared__ float red[4];
  const int row = blockIdx.x, tid = threadIdx.x;
  const unsigned short* p = in + (size_t)row * 1024 + tid * 4;
  const ushort4 u = *(const ushort4*)p;
  float x[4] = {bf2f(u.x), bf2f(u.y), bf2f(u.z), bf2f(u.w)};
  float ss = x[0] * x[0] + x[1] * x[1] + x[2] * x[2] + x[3] * x[3];
  for (int off = 32; off > 0; off >>= 1) ss += __shfl_down(ss, off, 64);
  if ((tid & 63) == 0) red[tid >> 6] = ss;
  __syncthreads();
  const float tot = red[0] + red[1] + red[2] + red[3];
  const float sc = 1.0f / fmaxf(sqrtf(tot), 1e-12f);
  float y[4];
  for (int j = 0; j < 4; ++j) {
    y[j] = x[j] * sc;
    if (do_gelu) y[j] = 0.5f * y[j] * (1.0f + erff(y[j] * 0.70710678118654752f));
  }
  if (fin && *flag == 0) {
    float4 o = {y[0], y[1], y[2], y[3]};
    ((float4*)out)[(size_t)row * 256 + tid] = o;
  } else {
    ushort4 o = {f2bf(y[0]), f2bf(y[1]), f2bf(y[2]), f2bf(y[3])};
    ((ushort4*)out)[(size_t)row * 256 + tid] = o;
  }
}

// ---------------------------------------------------------------------------
extern "C" void kernel_launch(void* const* d_in, const int* in_sizes, int n_in,
                              void* d_out, int out_size, void* d_ws, size_t ws_size,
                              hipStream_t stream)
{
  const void* x   = d_in[0];
  const void* Wq  = d_in[1];
  const void* Wk  = d_in[2];
  const void* Wv  = d_in[3];
  const void* Wo  = d_in[4];
  const void* Wff = d_in[5];

  char* ws = (char*)d_ws;
  size_t off = 0;
  auto alloc = [&](size_t bytes) -> void* {
    void* p = ws + off; off += (bytes + 255) & ~(size_t)255; return p;
  };
  int* flag             = (int*)alloc(256);
  unsigned short* xb    = (unsigned short*)alloc((size_t)4096 * 1024 * 2);  // 8 MB
  unsigned short* WT    = (unsigned short*)alloc((size_t)5 * 1024 * 1024 * 2); // 10 MB
  unsigned short* QKV   = (unsigned short*)alloc((size_t)4096 * 3072 * 2);  // 24 MB
  unsigned short* Vt    = (unsigned short*)alloc((size_t)32 * 64 * 2048 * 2); // 8 MB
  float* spart          = (float*)alloc((size_t)4 * 65536 * 4);             // 1 MB
  float* rsum           = (float*)alloc((size_t)65536 * 4);                 // 256 KB
  unsigned short* z1    = (unsigned short*)alloc((size_t)4096 * 1024 * 2);  // 8 MB
  unsigned short* WTqkv = WT;                          // slots 0..2
  unsigned short* WoT   = WT + (size_t)3 * 1024 * 1024;
  unsigned short* WffT  = WT + (size_t)4 * 1024 * 1024;
  // aliases onto dead regions:
  unsigned short* z2  = Vt;    // Vt dead after attn_pv
  unsigned short* z2n = xb;    // xb dead after QKV gemm
  unsigned short* z3  = QKV;   // QKV dead after attn_pv

  detect_dtype<<<1, 256, 0, stream>>>((const unsigned int*)x, flag);
  cvt_x<<<2048, 256, 0, stream>>>(x, xb, flag);
  w_transpose5<<<dim3(16, 16, 5), 256, 0, stream>>>(Wq, Wk, Wv, Wo, Wff, WT, flag);

  // fused QKV projection (Q columns pre-scaled by 0.03125*log2e), 128x128 tile
  gemm_bt_128x128<<<dim3(32, 24), 256, 0, stream>>>(xb, WTqkv, QKV,
                                                    4096, 3072, 1024, 1024, 1024, 3072, 1024);
  attn_stats<<<dim3(32, 16, 4), 256, 0, stream>>>(QKV, spart);
  stats_combine<<<256, 256, 0, stream>>>(spart, rsum);
  v_transpose<<<dim3(32, 32), 256, 0, stream>>>(QKV, rsum, Vt);
  attn_pv<<<dim3(32, 16), 256, 0, stream>>>(QKV, Vt, z1);

  gemm_bt_128x64<<<dim3(32, 16), 256, 0, stream>>>(z1, WoT, z2,
                                                   4096, 1024, 1024, 1024, 1024, 1024, 0);
  l2norm_gelu<<<4096, 256, 0, stream>>>(z2, z2n, 0, 0, flag);
  gemm_bt_128x64<<<dim3(32, 16), 256, 0, stream>>>(z2n, WffT, z3,
                                                   4096, 1024, 1024, 1024, 1024, 1024, 0);
  l2norm_gelu<<<4096, 256, 0, stream>>>(z3, d_out, 1, 1, flag);
}

// Round 8
// 287.692 us; speedup vs baseline: 1.4059x; 1.0359x over previous
//
#include <hip/hip_runtime.h>
#include <hip/hip_bf16.h>
#include <stdint.h>

// ---------------------------------------------------------------------------
// DecoderOnlyTransformer: x@Wq/Wk/Wv -> transposed-softmax attention -> @Wo
//   -> (l2norm dropped: exact cancellation) -> @Wff -> l2norm -> gelu(exact).
// B=2 S=2048 D=L=1024 H=16 dh=64.  Inputs fp32 (auto-detect fallback).
// Softmax over QUERY axis; |scores|<1 so max-subtraction dropped (exact).
// Q pre-scaled by 0.03125*log2(e); V rows pre-scaled by r_k.
// attn_pv2: S computed in D[k][q] layout whose C-regs ARE the B-operand of
// mfma 16x16x16 -> P never touches LDS (round-6 was LDS-pipe-bound).
// LESSON (round 7 crash): never gate LAUNCH-site code on __has_builtin —
// it diverges between host and device compilation passes.
// ---------------------------------------------------------------------------

typedef __attribute__((ext_vector_type(8))) short short8;   // 8 x bf16
typedef __attribute__((ext_vector_type(4))) short short4v;  // 4 x bf16
typedef __attribute__((ext_vector_type(4))) float floatx4;

#define MFMA_BF16(a, b, c) __builtin_amdgcn_mfma_f32_16x16x32_bf16((a), (b), (c), 0, 0, 0)
// v_mfma_f32_16x16x16_bf16 (cdna4_isa.md §10) — used in device code only.
#define MFMA16(a, b, c) __builtin_amdgcn_mfma_f32_16x16x16bf16_1k((a), (b), (c), 0, 0, 0)

#if defined(__HIP_DEVICE_COMPILE__)
#define EXP2F(x) __builtin_amdgcn_exp2f(x)
#else
#define EXP2F(x) exp2f(x)
#endif

__device__ __forceinline__ float bf2f(unsigned short u) {
  union { unsigned int i; float f; } v; v.i = ((unsigned int)u) << 16; return v.f;
}
__device__ __forceinline__ unsigned short f2bf(float f) {
  __hip_bfloat16 h = __float2bfloat16(f);
  return *reinterpret_cast<unsigned short*>(&h);
}
__device__ __forceinline__ void gld_lds16(const void* g, void* l) {
  __builtin_amdgcn_global_load_lds((__attribute__((address_space(1))) void*)g,
                                   (__attribute__((address_space(3))) void*)l,
                                   16, 0, 0);
}

// ---------------------------------------------------------------------------
__global__ __launch_bounds__(256) void detect_dtype(const unsigned int* __restrict__ x,
                                                    int* __restrict__ flag)
{
  __shared__ int red[4];
  int ok = 0;
  for (int i = 0; i < 16; ++i) {
    const unsigned int w = x[threadIdx.x * 16 + i];
    const unsigned int e = (w >> 7) & 0xFF;
    ok += (e == 0 || (e >= 96 && e <= 144)) ? 1 : 0;
  }
  for (int off = 32; off > 0; off >>= 1) ok += __shfl_down(ok, off, 64);
  if ((threadIdx.x & 63) == 0) red[threadIdx.x >> 6] = ok;
  __syncthreads();
  if (threadIdx.x == 0)
    *flag = ((red[0] + red[1] + red[2] + red[3]) > 2048) ? 1 : 0;
}

__global__ __launch_bounds__(256) void cvt_x(const void* __restrict__ src,
                                             unsigned short* __restrict__ dst,
                                             const int* __restrict__ flag)
{
  const int i = blockIdx.x * 256 + threadIdx.x;
  if (*flag) {
    ((uint4*)dst)[i] = ((const uint4*)src)[i];
  } else {
    const float4 a = ((const float4*)src)[2 * i];
    const float4 b = ((const float4*)src)[2 * i + 1];
    unsigned short o[8] = {f2bf(a.x), f2bf(a.y), f2bf(a.z), f2bf(a.w),
                           f2bf(b.x), f2bf(b.y), f2bf(b.z), f2bf(b.w)};
    ((uint4*)dst)[i] = *(uint4*)o;
  }
}

// ---------------------------------------------------------------------------
// C[M,N] = A[M,K] @ Bt[N,K]^T, tile 128x64, BK=32.
// ---------------------------------------------------------------------------
__global__ __launch_bounds__(256) void gemm_bt_128x64(
    const unsigned short* __restrict__ A, const unsigned short* __restrict__ Bt,
    unsigned short* __restrict__ C, int M, int N, int K, int lda, int ldb, int ldc,
    int qscale_cols)
{
  __shared__ __align__(16) unsigned short sA[128 * 32];
  __shared__ __align__(16) unsigned short sB[64 * 32];
  const int tid = threadIdx.x;
  const int wave = tid >> 6, lane = tid & 63, l15 = lane & 15, quad = lane >> 4;
  const int m0 = blockIdx.x * 128, n0 = blockIdx.y * 64;

  const floatx4 z4 = {0.f, 0.f, 0.f, 0.f};
  floatx4 acc[2][4];
  for (int i = 0; i < 2; ++i) for (int j = 0; j < 4; ++j) acc[i][j] = z4;

  const int NK = K >> 5;
  auto stage = [&](int kt) {
    const int k0 = kt << 5;
    for (int j = 0; j < 2; ++j) {
      const int ci = j * 256 + wave * 64 + lane;
      gld_lds16(A + (size_t)(m0 + (ci >> 2)) * lda + k0 + (ci & 3) * 8,
                &sA[(j * 256 + wave * 64) * 8]);
    }
    {
      const int ci = wave * 64 + lane;
      gld_lds16(Bt + (size_t)(n0 + (ci >> 2)) * ldb + k0 + (ci & 3) * 8,
                &sB[(wave * 64) * 8]);
    }
  };

  stage(0);
  for (int kt = 0; kt < NK; ++kt) {
    __syncthreads();
    short8 af[2], bf[4];
    for (int mt = 0; mt < 2; ++mt)
      af[mt] = *(const short8*)&sA[(wave * 32 + mt * 16 + l15) * 32 + quad * 8];
    for (int nt = 0; nt < 4; ++nt)
      bf[nt] = *(const short8*)&sB[(nt * 16 + l15) * 32 + quad * 8];
    for (int mt = 0; mt < 2; ++mt)
      for (int nt = 0; nt < 4; ++nt)
        acc[mt][nt] = MFMA_BF16(af[mt], bf[nt], acc[mt][nt]);
    __syncthreads();
    if (kt + 1 < NK) stage(kt + 1);
  }
  for (int mt = 0; mt < 2; ++mt)
    for (int nt = 0; nt < 4; ++nt)
      for (int r = 0; r < 4; ++r) {
        const int row = m0 + wave * 32 + mt * 16 + quad * 4 + r;
        const int col = n0 + nt * 16 + l15;
        float v = acc[mt][nt][r];
        if (col < qscale_cols) v *= 0.04508422f;
        C[(size_t)row * ldc + col] = f2bf(v);
      }
}

// ---------------------------------------------------------------------------
// C[M,N] = A[M,K] @ Bt[N,K]^T, tile 128x128 (m97 shape), BK=32, 2x2 waves.
// ---------------------------------------------------------------------------
__global__ __launch_bounds__(256) void gemm_bt_128x128(
    const unsigned short* __restrict__ A, const unsigned short* __restrict__ Bt,
    unsigned short* __restrict__ C, int M, int N, int K, int lda, int ldb, int ldc,
    int qscale_cols)
{
  __shared__ __align__(16) unsigned short sA[128 * 32];
  __shared__ __align__(16) unsigned short sB[128 * 32];
  const int tid = threadIdx.x;
  const int wave = tid >> 6, lane = tid & 63, l15 = lane & 15, quad = lane >> 4;
  const int wr = wave >> 1, wc = wave & 1;
  const int m0 = blockIdx.x * 128, n0 = blockIdx.y * 128;

  const floatx4 z4 = {0.f, 0.f, 0.f, 0.f};
  floatx4 acc[4][4];
  for (int i = 0; i < 4; ++i) for (int j = 0; j < 4; ++j) acc[i][j] = z4;

  const int NK = K >> 5;
  auto stage = [&](int kt) {
    const int k0 = kt << 5;
    for (int j = 0; j < 2; ++j) {
      const int ci = j * 256 + wave * 64 + lane;
      gld_lds16(A + (size_t)(m0 + (ci >> 2)) * lda + k0 + (ci & 3) * 8,
                &sA[(j * 256 + wave * 64) * 8]);
      gld_lds16(Bt + (size_t)(n0 + (ci >> 2)) * ldb + k0 + (ci & 3) * 8,
                &sB[(j * 256 + wave * 64) * 8]);
    }
  };

  stage(0);
  for (int kt = 0; kt < NK; ++kt) {
    __syncthreads();
    short8 af[4], bf[4];
    for (int mt = 0; mt < 4; ++mt)
      af[mt] = *(const short8*)&sA[(wr * 64 + mt * 16 + l15) * 32 + quad * 8];
    for (int nt = 0; nt < 4; ++nt)
      bf[nt] = *(const short8*)&sB[(wc * 64 + nt * 16 + l15) * 32 + quad * 8];
    for (int mt = 0; mt < 4; ++mt)
      for (int nt = 0; nt < 4; ++nt)
        acc[mt][nt] = MFMA_BF16(af[mt], bf[nt], acc[mt][nt]);
    __syncthreads();
    if (kt + 1 < NK) stage(kt + 1);
  }
  for (int mt = 0; mt < 4; ++mt)
    for (int nt = 0; nt < 4; ++nt)
      for (int r = 0; r < 4; ++r) {
        const int row = m0 + wr * 64 + mt * 16 + quad * 4 + r;
        const int col = n0 + wc * 64 + nt * 16 + l15;
        float v = acc[mt][nt][r];
        if (col < qscale_cols) v *= 0.04508422f;
        C[(size_t)row * ldc + col] = f2bf(v);
      }
}

// ---------------------------------------------------------------------------
// Fused 5x weight transpose (+dtype convert)
// ---------------------------------------------------------------------------
__global__ __launch_bounds__(256) void w_transpose5(
    const void* __restrict__ W0, const void* __restrict__ W1,
    const void* __restrict__ W2, const void* __restrict__ W3,
    const void* __restrict__ W4, unsigned short* __restrict__ WT,
    const int* __restrict__ flag)
{
  __shared__ __align__(16) unsigned short tile[64 * 72];
  const void* srcs[5] = {W0, W1, W2, W3, W4};
  const void* W = srcs[blockIdx.z];
  unsigned short* dst0 = WT + (size_t)blockIdx.z * 1024 * 1024;
  const int rb = blockIdx.x * 64, cb = blockIdx.y * 64;
  const int tid = threadIdx.x;
  const int r = tid >> 2, c = tid & 3;
  unsigned short tmp[16];
  if (*flag) {
    const unsigned short* src = (const unsigned short*)W + (size_t)(rb + r) * 1024 + cb + c * 16;
    *(uint4*)&tmp[0] = *(const uint4*)src;
    *(uint4*)&tmp[8] = *(const uint4*)(src + 8);
  } else {
    const float* src = (const float*)W + (size_t)(rb + r) * 1024 + cb + c * 16;
    for (int j = 0; j < 16; j += 4) {
      const float4 f = *(const float4*)(src + j);
      tmp[j + 0] = f2bf(f.x); tmp[j + 1] = f2bf(f.y);
      tmp[j + 2] = f2bf(f.z); tmp[j + 3] = f2bf(f.w);
    }
  }
  *(uint4*)&tile[r * 72 + c * 16] = *(uint4*)&tmp[0];
  *(uint4*)&tile[r * 72 + c * 16 + 8] = *(uint4*)&tmp[8];
  __syncthreads();
  const int oc = tid >> 2;
  unsigned short out[16];
  for (int j = 0; j < 16; ++j) out[j] = tile[(c * 16 + j) * 72 + oc];
  unsigned short* dst = dst0 + (size_t)(cb + oc) * 1024 + rb + c * 16;
  *(uint4*)dst = *(uint4*)&out[0];
  *(uint4*)(dst + 8) = *(uint4*)&out[8];
}

// ---------------------------------------------------------------------------
// V-transpose + r_k scaling (rsum computed inline from 4 partials):
// Vt[bh][d][s] = V[b,s,h*64+d] / sum_qs spart[(bh*2048+s)*4 + qs]
// ---------------------------------------------------------------------------
__global__ __launch_bounds__(256) void v_transpose(const unsigned short* __restrict__ QKV,
                                                   const float* __restrict__ spart,
                                                   unsigned short* __restrict__ Vt)
{
  __shared__ __align__(16) unsigned short tile[64 * 72];
  const int bh = blockIdx.x, st = blockIdx.y;
  const int b = bh >> 4, h = bh & 15;
  const int tid = threadIdx.x;
  const int r = tid >> 2, c = tid & 3;
  const unsigned short* src =
      QKV + (size_t)(b * 2048 + st * 64 + r) * 3072 + 2048 + h * 64 + c * 16;
  *(uint4*)&tile[r * 72 + c * 16] = *(const uint4*)src;
  *(uint4*)&tile[r * 72 + c * 16 + 8] = *(const uint4*)(src + 8);
  __syncthreads();
  const int d = tid >> 2;
  unsigned short out[16];
  for (int j = 0; j < 16; ++j) {
    const int s = st * 64 + c * 16 + j;
    const float4 sp = *(const float4*)&spart[(size_t)(bh * 2048 + s) * 4];
    const float rs = 1.0f / (sp.x + sp.y + sp.z + sp.w);
    out[j] = f2bf(bf2f(tile[(c * 16 + j) * 72 + d]) * rs);
  }
  unsigned short* dst = Vt + (size_t)bh * 64 * 2048 + (size_t)d * 2048 + st * 64 + c * 16;
  *(uint4*)dst = *(uint4*)&out[0];
  *(uint4*)(dst + 8) = *(uint4*)&out[8];
}

// ---------------------------------------------------------------------------
// Attention stats: spart[(bh*2048+k)*4 + qs] = sum_{q in 512-quarter} exp2(<K,Q'>)
// ---------------------------------------------------------------------------
__global__ __launch_bounds__(256) void attn_stats(const unsigned short* __restrict__ QKV,
                                                  float* __restrict__ spart)
{
  __shared__ __align__(16) unsigned short sQ[2][8 * 512];
  const int bh = blockIdx.x, kb = blockIdx.y, qs = blockIdx.z;
  const int b = bh >> 4, h = bh & 15;
  const int tid = threadIdx.x;
  const int wave = tid >> 6, lane = tid & 63, l15 = lane & 15, quad = lane >> 4;
  const int kbase = kb * 128 + wave * 32;
  const size_t row0 = (size_t)b * 2048;
  const int qoff = h * 64, koff = 1024 + h * 64;
  const int qbase = qs * 512;

  short8 kf[2][2];
  for (int rt = 0; rt < 2; ++rt)
    for (int ks = 0; ks < 2; ++ks)
      kf[rt][ks] = *(const short8*)&QKV[(row0 + kbase + rt * 16 + l15) * 3072 +
                                        koff + ks * 32 + quad * 8];

  float l[2][4];
  for (int rt = 0; rt < 2; ++rt)
    for (int r = 0; r < 4; ++r) l[rt][r] = 0.f;

  auto stageQ = [&](int t) {
    const int qt0 = qbase + t * 64;
    for (int j = 0; j < 2; ++j) {
      const int f = wave * 2 + j;
      const int nt = f >> 1, ks = f & 1;
      gld_lds16(QKV + (row0 + qt0 + nt * 16 + l15) * 3072 + qoff + ks * 32 + quad * 8,
                &sQ[t & 1][f * 512]);
    }
  };

  const floatx4 z4 = {0.f, 0.f, 0.f, 0.f};
  stageQ(0);
  for (int t = 0; t < 8; ++t) {
    __syncthreads();
    if (t + 1 < 8) stageQ(t + 1);
    const unsigned short* sQt = sQ[t & 1];
    for (int nt = 0; nt < 4; ++nt) {
      const short8 bq0 = *(const short8*)&sQt[(nt * 2 + 0) * 512 + lane * 8];
      const short8 bq1 = *(const short8*)&sQt[(nt * 2 + 1) * 512 + lane * 8];
      for (int rt = 0; rt < 2; ++rt) {
        floatx4 acc = z4;
        acc = MFMA_BF16(kf[rt][0], bq0, acc);
        acc = MFMA_BF16(kf[rt][1], bq1, acc);
        for (int r = 0; r < 4; ++r)
          l[rt][r] += EXP2F(acc[r]);
      }
    }
  }
  for (int rt = 0; rt < 2; ++rt)
    for (int r = 0; r < 4; ++r) {
      float ll = l[rt][r];
      ll += __shfl_xor(ll, 1, 64);
      ll += __shfl_xor(ll, 2, 64);
      ll += __shfl_xor(ll, 4, 64);
      ll += __shfl_xor(ll, 8, 64);
      if (l15 == 0) {
        const int krow = kbase + rt * 16 + quad * 4 + r;
        spart[(size_t)(bh * 2048 + krow) * 4 + qs] = ll;
      }
    }
}

// ---------------------------------------------------------------------------
// attn_pv2: Outp[kh][q,d] = sum_{k in half} exp2(<Q'_q,K_k>) * V'[k,d]
// S computed as D[k][q] (A=K, B=Q): its C-regs (k=quad*4+r, q=l15) are
// EXACTLY the B-operand layout of mfma_f32_16x16x16_bf16 -> P stays in regs.
// PV: A = V'-frag (m=d), accumulate Out^T[d][q]; one LDS transpose at end.
// grid (32 bh, 16 qb of 128, 2 k-halves); 4 waves x 32 q; k-tiles 64 dbuf.
// LDS 32 KB -> 4 blocks/CU (grid-limited) = 16 waves/CU.
// ---------------------------------------------------------------------------
__global__ __launch_bounds__(256) void attn_pv2(const unsigned short* __restrict__ QKV,
                                                const unsigned short* __restrict__ Vt,
                                                unsigned short* __restrict__ z1p0,
                                                unsigned short* __restrict__ z1p1)
{
  __shared__ __align__(16) unsigned char smem[32768];
  unsigned short* sK = (unsigned short*)smem;            // [2][64*64]
  unsigned short* sV = (unsigned short*)(smem + 16384);  // [2][64*64]
  unsigned short* sT = (unsigned short*)smem;            // [128][72] (epilogue)

  const int bh = blockIdx.x, qb = blockIdx.y, kh = blockIdx.z;
  const int b = bh >> 4, h = bh & 15;
  const int tid = threadIdx.x;
  const int wave = tid >> 6, lane = tid & 63, l15 = lane & 15, quad = lane >> 4;
  const size_t row0 = (size_t)b * 2048;
  const int qoff = h * 64, koff = 1024 + h * 64;
  const int q0 = qb * 128;
  const int srow = lane >> 3, schk = (lane & 7) ^ ((lane >> 3) & 7);

  // Q B-frags (B[dh][q], lane l15 = q), held in regs for the whole kernel
  short8 qf[2][2];  // [qg][ks]
  for (int qg = 0; qg < 2; ++qg)
    for (int ks = 0; ks < 2; ++ks)
      qf[qg][ks] = *(const short8*)&QKV[(row0 + q0 + wave * 32 + qg * 16 + l15) * 3072 +
                                        qoff + ks * 32 + quad * 8];

  const floatx4 z4 = {0.f, 0.f, 0.f, 0.f};
  floatx4 acc[4][2];  // [dg][qg] : Out^T[d][q]
  for (int i = 0; i < 4; ++i) for (int j = 0; j < 2; ++j) acc[i][j] = z4;

  const unsigned short* VtB = Vt + (size_t)bh * 64 * 2048;

  auto stage = [&](int kt) {
    const int kb = kh * 1024 + kt * 64;
    const int bo = (kt & 1) * 4096;
    for (int j = 0; j < 2; ++j) {
      const int jj = wave * 2 + j;  // 8-row group
      gld_lds16(QKV + (row0 + kb + jj * 8 + srow) * 3072 + koff + schk * 8,
                &sK[bo + jj * 512]);
      gld_lds16(VtB + (size_t)(jj * 8 + srow) * 2048 + kb + schk * 8,
                &sV[bo + jj * 512]);
    }
  };

  stage(0);
  for (int kt = 0; kt < 16; ++kt) {
    __syncthreads();
    if (kt + 1 < 16) stage(kt + 1);
    const unsigned short* sKt = &sK[(kt & 1) * 4096];
    const unsigned short* sVt = &sV[(kt & 1) * 4096];
    for (int kg = 0; kg < 4; ++kg) {     // 16-k groups in the 64-k tile
      // --- S tile D[k][q] for this kg: A = K rows, B = Q ---
      floatx4 s0 = z4, s1 = z4;
      for (int ks = 0; ks < 2; ++ks) {
        const short8 kfr = *(const short8*)
            &sKt[(kg * 16 + l15) * 64 + (((ks * 4 + quad) ^ (l15 & 7)) * 8)];
        s0 = MFMA_BF16(kfr, qf[0][ks], s0);
        s1 = MFMA_BF16(kfr, qf[1][ks], s1);
      }
      // --- P frags in regs: lane holds P[k=quad*4+r][q=l15] = B-op of K16 ---
      union PU { struct { __hip_bfloat162 lo, hi; } p; short4v v; };
      PU p0, p1;
      p0.p.lo = __float22bfloat162_rn(float2{EXP2F(s0[0]), EXP2F(s0[1])});
      p0.p.hi = __float22bfloat162_rn(float2{EXP2F(s0[2]), EXP2F(s0[3])});
      p1.p.lo = __float22bfloat162_rn(float2{EXP2F(s1[0]), EXP2F(s1[1])});
      p1.p.hi = __float22bfloat162_rn(float2{EXP2F(s1[2]), EXP2F(s1[3])});
      // --- Out^T += V'^T-frag @ P : A[m=d][k=quad*4+j] from sV b64 reads ---
      const int slot = (2 * kg + (quad >> 1)) ^ (l15 & 7);
      const int sub = (quad & 1) * 8;
      for (int dg = 0; dg < 4; ++dg) {
        const short4v vfr = *(const short4v*)
            ((const char*)&sVt[(dg * 16 + l15) * 64] + slot * 16 + sub);
        acc[dg][0] = MFMA16(vfr, p0.v, acc[dg][0]);
        acc[dg][1] = MFMA16(vfr, p1.v, acc[dg][1]);
      }
    }
  }
  // epilogue: transpose Out^T[d][q] -> [q][d] via LDS, store coalesced
  __syncthreads();
  for (int dg = 0; dg < 4; ++dg)
    for (int qg = 0; qg < 2; ++qg) {
      ushort4 pk = {f2bf(acc[dg][qg][0]), f2bf(acc[dg][qg][1]),
                    f2bf(acc[dg][qg][2]), f2bf(acc[dg][qg][3])};
      *(ushort4*)&sT[(wave * 32 + qg * 16 + l15) * 72 + dg * 16 + quad * 4] = pk;
    }
  __syncthreads();
  unsigned short* z1p = kh ? z1p1 : z1p0;
  const int q = tid >> 1, d0 = (tid & 1) * 32;
  unsigned short* dst = z1p + (row0 + q0 + q) * 1024 + qoff + d0;
  const unsigned short* srcT = &sT[q * 72 + d0];
  for (int j = 0; j < 4; ++j)
    *(uint4*)(dst + j * 8) = *(const uint4*)(srcT + j * 8);
}

// z1 = bf16(z1p0 + z1p1), 4096x1024 elements, 8 per thread
__global__ __launch_bounds__(256) void pv_combine(const unsigned short* __restrict__ z1p0,
                                                  const unsigned short* __restrict__ z1p1,
                                                  unsigned short* __restrict__ z1)
{
  const int i = blockIdx.x * 256 + threadIdx.x;
  const uint4 a = ((const uint4*)z1p0)[i];
  const uint4 b = ((const uint4*)z1p1)[i];
  const unsigned short* av = (const unsigned short*)&a;
  const unsigned short* bv = (const unsigned short*)&b;
  unsigned short o[8];
  for (int j = 0; j < 8; ++j) o[j] = f2bf(bf2f(av[j]) + bf2f(bv[j]));
  ((uint4*)z1)[i] = *(uint4*)o;
}

// ---------------------------------------------------------------------------
// Row-wise L2 normalize (1024 cols) + exact-erf GELU.  1 block/row.
// ---------------------------------------------------------------------------
__global__ __launch_bounds__(256) void l2norm_gelu(const unsigned short* __restrict__ in,
                                                   void* __restrict__ out, int do_gelu,
                                                   int fin, const int* __restrict__ flag)
{
  __shared__ float red[4];
  const int row = blockIdx.x, tid = threadIdx.x;
  const unsigned short* p = in + (size_t)row * 1024 + tid * 4;
  const ushort4 u = *(const ushort4*)p;
  float x[4] = {bf2f(u.x), bf2f(u.y), bf2f(u.z), bf2f(u.w)};
  float ss = x[0] * x[0] + x[1] * x[1] + x[2] * x[2] + x[3] * x[3];
  for (int off = 32; off > 0; off >>= 1) ss += __shfl_down(ss, off, 64);
  if ((tid & 63) == 0) red[tid >> 6] = ss;
  __syncthreads();
  const float tot = red[0] + red[1] + red[2] + red[3];
  const float sc = 1.0f / fmaxf(sqrtf(tot), 1e-12f);
  float y[4];
  for (int j = 0; j < 4; ++j) {
    y[j] = x[j] * sc;
    if (do_gelu) y[j] = 0.5f * y[j] * (1.0f + erff(y[j] * 0.70710678118654752f));
  }
  if (fin && *flag == 0) {
    float4 o = {y[0], y[1], y[2], y[3]};
    ((float4*)out)[(size_t)row * 256 + tid] = o;
  } else {
    ushort4 o = {f2bf(y[0]), f2bf(y[1]), f2bf(y[2]), f2bf(y[3])};
    ((ushort4*)out)[(size_t)row * 256 + tid] = o;
  }
}

// ---------------------------------------------------------------------------
extern "C" void kernel_launch(void* const* d_in, const int* in_sizes, int n_in,
                              void* d_out, int out_size, void* d_ws, size_t ws_size,
                              hipStream_t stream)
{
  const void* x   = d_in[0];
  const void* Wq  = d_in[1];
  const void* Wk  = d_in[2];
  const void* Wv  = d_in[3];
  const void* Wo  = d_in[4];
  const void* Wff = d_in[5];

  char* ws = (char*)d_ws;
  size_t off = 0;
  auto alloc = [&](size_t bytes) -> void* {
    void* p = ws + off; off += (bytes + 255) & ~(size_t)255; return p;
  };
  int* flag             = (int*)alloc(256);
  unsigned short* xb    = (unsigned short*)alloc((size_t)4096 * 1024 * 2);  // 8 MB
  unsigned short* WT    = (unsigned short*)alloc((size_t)5 * 1024 * 1024 * 2); // 10 MB
  unsigned short* QKV   = (unsigned short*)alloc((size_t)4096 * 3072 * 2);  // 24 MB
  unsigned short* Vt    = (unsigned short*)alloc((size_t)32 * 64 * 2048 * 2); // 8 MB
  float* spart          = (float*)alloc((size_t)65536 * 4 * 4);             // 1 MB
  unsigned short* z1    = (unsigned short*)alloc((size_t)4096 * 1024 * 2);  // 8 MB
  unsigned short* z1p1  = (unsigned short*)alloc((size_t)4096 * 1024 * 2);  // 8 MB
  unsigned short* WTqkv = WT;
  unsigned short* WoT   = WT + (size_t)3 * 1024 * 1024;
  unsigned short* WffT  = WT + (size_t)4 * 1024 * 1024;
  // aliases onto dead regions:
  unsigned short* z1p0 = xb;    // xb dead after QKV gemm
  unsigned short* z2   = Vt;    // Vt dead after attn_pv2
  unsigned short* z3   = QKV;   // QKV dead after attn_pv2

  detect_dtype<<<1, 256, 0, stream>>>((const unsigned int*)x, flag);
  cvt_x<<<2048, 256, 0, stream>>>(x, xb, flag);
  w_transpose5<<<dim3(16, 16, 5), 256, 0, stream>>>(Wq, Wk, Wv, Wo, Wff, WT, flag);

  gemm_bt_128x128<<<dim3(32, 24), 256, 0, stream>>>(xb, WTqkv, QKV,
                                                    4096, 3072, 1024, 1024, 1024, 3072, 1024);
  attn_stats<<<dim3(32, 16, 4), 256, 0, stream>>>(QKV, spart);
  v_transpose<<<dim3(32, 32), 256, 0, stream>>>(QKV, spart, Vt);
  attn_pv2<<<dim3(32, 16, 2), 256, 0, stream>>>(QKV, Vt, z1p0, z1p1);
  pv_combine<<<2048, 256, 0, stream>>>(z1p0, z1p1, z1);

  gemm_bt_128x64<<<dim3(32, 16), 256, 0, stream>>>(z1, WoT, z2,
                                                   4096, 1024, 1024, 1024, 1024, 1024, 0);
  // first l2norm dropped: l2norm(l2norm(z2)@Wff) == l2norm(z2@Wff) exactly
  gemm_bt_128x64<<<dim3(32, 16), 256, 0, stream>>>(z2, WffT, z3,
                                                   4096, 1024, 1024, 1024, 1024, 1024, 0);
  l2norm_gelu<<<4096, 256, 0, stream>>>(z3, d_out, 1, 1, flag);
}